// Round 1
// baseline (875.651 us; speedup 1.0000x reference)
//
#include <hip/hip_runtime.h>
#include <cstdint>
#include <cstddef>

// ---------------------------------------------------------------------------
// Graph_8564164788735: 2-layer class-conditioned GRU-ish propagation.
// N=1024 nodes, C=128 classes, H=256. Output fp32 [N,C,H].
//
// Design:
//  Layer 1 exploits rank-1 structure (hidden0 = broadcast x): gates come from
//  one small GEMM XW = x @ Wcat^T plus scalars colsum/rowsum per class.
//  Layer 2: av = shared(hs) - node(hidden). Shared part in fp32 (tiny FLOPs),
//  node part via bf16 MFMA GEMMs:
//    nodeAB: AVH[:,0:512] = [-K^T Hid_n | -K Hid_n]  (generic gemm w/ A-row
//            mask 127 and per-mtile B stride on transposed hidden)
//    PRE = AVH|H1 @ WB  (one [131072,768]x[768,768] GEMM; u3 folded in)
//    T   = (r*h) @ u5^T
//  Elementwise kernels apply sigmoid/tanh and the GRU update.
// ---------------------------------------------------------------------------

#define NODES 1024
#define NCLS  128
#define HID   256
#define NC_ROWS (NODES*NCLS)   // 131072

using frag  = __attribute__((ext_vector_type(8))) short;
using f32x4 = __attribute__((ext_vector_type(4))) float;

__device__ __forceinline__ float bf2f(unsigned short h){
  unsigned int u = ((unsigned int)h) << 16;
  float f; __builtin_memcpy(&f, &u, 4); return f;
}
__device__ __forceinline__ unsigned short f2bf(float f){
  unsigned int u; __builtin_memcpy(&u, &f, 4);
  u = (u + 0x7fffu + ((u >> 16) & 1u)) >> 16;   // RNE
  return (unsigned short)u;
}
__device__ __forceinline__ float sigm(float x){ return 1.0f/(1.0f + __expf(-x)); }
__device__ __forceinline__ float tanh_fast(float x){ return 1.0f - 2.0f/(__expf(2.0f*x) + 1.0f); }

#define GLOBAL_AS(p) ((const __attribute__((address_space(1))) void*)(p))
#define LDS_AS(p)    ((__attribute__((address_space(3))) void*)(p))

// ---------------------------------------------------------------------------
// Generic bf16 MFMA GEMM, 128x128 tile, BK=32, 256 threads (4 waves, 2x2).
// C[row,col] = sum_k A(row,k) * BT[col,k]
// A(row,k): k <  K0 -> A0[(row & aMask)*ldA0 + k]
//           k >= K0 -> A1[row*ldA1 + (k-K0)]
// BT effective base = BT + mtile*bStride  (per-node batched B)
// ---------------------------------------------------------------------------
template<int OUT_BF16>
__global__ __launch_bounds__(256) void gemm_bf16(
    const unsigned short* __restrict__ A0, int ldA0, int K0,
    const unsigned short* __restrict__ A1, int ldA1,
    const unsigned short* __restrict__ BT, int ldB, long bStride,
    void* __restrict__ Cptr, int ldC,
    int Ntiles, int Ktot, unsigned int aMask)
{
  __shared__ unsigned short As[4096];   // [128 m][32 k]
  __shared__ unsigned short Bs[4096];   // [128 n][32 k]
  const int t   = threadIdx.x;
  const int bid = blockIdx.x;
  const int nt  = bid % Ntiles, mt = bid / Ntiles;
  const int lane = t & 63, w = t >> 6;
  const int wm = w >> 1, wn = w & 1;
  const int r = lane & 15, q = lane >> 4;
  const int m0 = mt * 128, n0 = nt * 128;
  const unsigned short* Bbase = BT + (size_t)mt * (size_t)bStride;

  f32x4 acc[4][4] = {};

  for (int kb = 0; kb < Ktot; kb += 32) {
#pragma unroll
    for (int i = 0; i < 2; ++i) {
      int u  = i * 256 + t;
      int mi = u >> 2;
      int kc = (u & 3) * 8;
      int k  = kb + kc;
      const unsigned short* ga;
      if (k < K0) ga = A0 + (size_t)((unsigned int)(m0 + mi) & aMask) * (size_t)ldA0 + k;
      else        ga = A1 + (size_t)(m0 + mi) * (size_t)ldA1 + (k - K0);
      __builtin_amdgcn_global_load_lds(GLOBAL_AS(ga), LDS_AS(&As[u * 8]), 16, 0, 0);
      const unsigned short* gb = Bbase + (size_t)(n0 + mi) * (size_t)ldB + k;
      __builtin_amdgcn_global_load_lds(GLOBAL_AS(gb), LDS_AS(&Bs[u * 8]), 16, 0, 0);
    }
    __syncthreads();

    frag af[4], bf_[4];
#pragma unroll
    for (int x = 0; x < 4; ++x) {
      af[x]  = *(const frag*)&As[(wm * 64 + x * 16 + r) * 32 + q * 8];
      bf_[x] = *(const frag*)&Bs[(wn * 64 + x * 16 + r) * 32 + q * 8];
    }
#pragma unroll
    for (int x = 0; x < 4; ++x)
#pragma unroll
      for (int y = 0; y < 4; ++y)
        acc[x][y] = __builtin_amdgcn_mfma_f32_16x16x32_bf16(af[x], bf_[y], acc[x][y], 0, 0, 0);
    __syncthreads();
  }

  // epilogue: D row = m-base + q*4+reg, col = n-base + (lane&15)
#pragma unroll
  for (int x = 0; x < 4; ++x) {
#pragma unroll
    for (int y = 0; y < 4; ++y) {
      int col = n0 + wn * 64 + y * 16 + r;
#pragma unroll
      for (int g = 0; g < 4; ++g) {
        long row = m0 + wm * 64 + x * 16 + q * 4 + g;
        if (OUT_BF16) ((unsigned short*)Cptr)[row * (long)ldC + col] = f2bf(acc[x][y][g]);
        else          ((float*)Cptr)[row * (long)ldC + col] = acc[x][y][g];
      }
    }
  }
}

// ---------------------------------------------------------------------------
// prep: bf16 casts + weight repacks.
// WB  [768 cols][768 j] : col=g*256+i (g: 0->w3,1->w4,2->w5); j<512: wg[i,j];
//                         j>=512: g<2 ? u3[i,j-512] : 0
// WB2 [1792 cols][256 h]: blocks 3L,3R,4L,4R,5L,5R,u3
// u5b [256][256] = u5 ; KbN[c][k] = -K[c,k] ; KTbN[c][k] = -K[k,c]
// ---------------------------------------------------------------------------
__global__ __launch_bounds__(256) void prep_cast(
    const float* __restrict__ x, const float* __restrict__ Kn,
    const float* __restrict__ w3, const float* __restrict__ u3,
    const float* __restrict__ w4, const float* __restrict__ w5,
    const float* __restrict__ u5,
    unsigned short* __restrict__ xb, unsigned short* __restrict__ WB,
    unsigned short* __restrict__ WB2, unsigned short* __restrict__ u5b,
    unsigned short* __restrict__ KbN, unsigned short* __restrict__ KTbN)
{
  int idx = blockIdx.x * 256 + threadIdx.x;
  if (idx < 262144) { xb[idx] = f2bf(x[idx]); return; }
  idx -= 262144;
  if (idx < 589824) {
    int col = idx / 768, j = idx % 768;
    int g = col >> 8, i = col & 255;
    float v;
    if (j < 512) { const float* wg = (g == 0) ? w3 : (g == 1) ? w4 : w5; v = wg[(size_t)i * 512 + j]; }
    else v = (g < 2) ? u3[(size_t)i * 256 + (j - 512)] : 0.0f;
    WB[(size_t)col * 768 + j] = f2bf(v);
    return;
  }
  idx -= 589824;
  if (idx < 458752) {
    int col = idx / 256, h = idx % 256;
    int b = col >> 8, i = col & 255;
    float v = (b < 6) ? ((b < 2 ? w3 : (b < 4 ? w4 : w5))[(size_t)i * 512 + (b & 1) * 256 + h])
                      : u3[(size_t)i * 256 + h];
    WB2[(size_t)col * 256 + h] = f2bf(v);
    return;
  }
  idx -= 458752;
  if (idx < 65536) { u5b[idx] = f2bf(u5[idx]); return; }
  idx -= 65536;
  if (idx < 16384) { int c = idx >> 7, k = idx & 127; KbN[idx]  = f2bf(-Kn[c * 128 + k]); return; }
  idx -= 16384;
  { int c = idx >> 7, k = idx & 127; KTbN[idx] = f2bf(-Kn[k * 128 + c]); }
}

// S[h] = sum_n x[n,h] (atomic, chunked); colsum[c]=sum_k K[k,c]; rowsum[c]=sum_k K[c,k]
__global__ __launch_bounds__(256) void prep_reduce(
    const float* __restrict__ x, const float* __restrict__ Kn,
    float* __restrict__ S, float* __restrict__ colsum, float* __restrict__ rowsum)
{
  int b = blockIdx.x, t = threadIdx.x;
  if (b < 8) {
    float s = 0.f;
    for (int n = 0; n < 128; ++n) s += x[(size_t)(b * 128 + n) * HID + t];
    atomicAdd(&S[t], s);
  } else if (b == 8) {
    if (t < NCLS) { float s = 0.f; for (int k = 0; k < NCLS; ++k) s += Kn[k * NCLS + t]; colsum[t] = s; }
  } else {
    if (t < NCLS) { float s = 0.f; for (int k = 0; k < NCLS; ++k) s += Kn[t * NCLS + k]; rowsum[t] = s; }
  }
}

// SW[col], col<1536 : sum_h S[h] * w-half(col)[h]   (fp32, layer-1 shared part)
__global__ __launch_bounds__(256) void prep_sw(
    const float* __restrict__ S, const float* __restrict__ w3,
    const float* __restrict__ w4, const float* __restrict__ w5, float* __restrict__ SW)
{
  int col = blockIdx.x * 256 + threadIdx.x;
  int b = col >> 8, i = col & 255;
  const float* w = (b < 2) ? w3 : (b < 4) ? w4 : w5;
  const float* row = w + (size_t)i * 512 + (b & 1) * 256;
  float s = 0.f;
  for (int h = 0; h < HID; ++h) s += S[h] * row[h];
  SW[col] = s;
}

// layer-1 r gate: RH1 = sigmoid(pre4) * x
__global__ __launch_bounds__(256) void e2_l1(
    const float* __restrict__ XW, const float* __restrict__ SW,
    const float* __restrict__ x, const float* __restrict__ b4,
    const float* __restrict__ bu3, const float* __restrict__ colsum,
    const float* __restrict__ rowsum, unsigned short* __restrict__ RH)
{
  int tid = blockIdx.x * 256 + threadIdx.x;
  int row = tid >> 5, i0 = (tid & 31) * 8;
  int n = row >> 7, c = row & 127;
  float cs = colsum[c], rs = rowsum[c];
  const float* xwn = XW + (size_t)n * 1792;
  frag out;
#pragma unroll
  for (int e = 0; e < 8; ++e) {
    int i = i0 + e;
    float pre = cs * (SW[512 + i] - xwn[512 + i]) + rs * (SW[768 + i] - xwn[768 + i])
              + xwn[1536 + i] + b4[i] + bu3[i];
    out[e] = (short)f2bf(sigm(pre) * x[(size_t)n * HID + i]);
  }
  *(frag*)(RH + (size_t)row * HID + i0) = out;
}

// layer-1 final: z, hv, h1 -> H1 (bf16)
__global__ __launch_bounds__(256) void e3_l1(
    const float* __restrict__ XW, const float* __restrict__ SW,
    const float* __restrict__ x,
    const float* __restrict__ b3, const float* __restrict__ bu3,
    const float* __restrict__ b5, const float* __restrict__ bu5,
    const float* __restrict__ colsum, const float* __restrict__ rowsum,
    const unsigned short* __restrict__ T1, unsigned short* __restrict__ H1)
{
  int tid = blockIdx.x * 256 + threadIdx.x;
  int row = tid >> 5, i0 = (tid & 31) * 8;
  int n = row >> 7, c = row & 127;
  float cs = colsum[c], rs = rowsum[c];
  const float* xwn = XW + (size_t)n * 1792;
  frag t1 = *(const frag*)(T1 + (size_t)row * HID + i0);
  frag out;
#pragma unroll
  for (int e = 0; e < 8; ++e) {
    int i = i0 + e;
    float z  = sigm(cs * (SW[i] - xwn[i]) + rs * (SW[256 + i] - xwn[256 + i])
               + xwn[1536 + i] + b3[i] + bu3[i]);
    float p5 = cs * (SW[1024 + i] - xwn[1024 + i]) + rs * (SW[1280 + i] - xwn[1280 + i])
             + b5[i] + bu5[i] + bf2f((unsigned short)t1[e]);
    float hv = tanh_fast(p5);
    float h1 = (1.0f - z) * x[(size_t)n * HID + i] + z * hv;
    out[e] = (short)f2bf(h1);
  }
  *(frag*)(H1 + (size_t)row * HID + i0) = out;
}

// H1 [n][k][h] -> H1T [n][h][k]  (64x64 LDS tiles)
__global__ __launch_bounds__(256) void transpose_h1(
    const unsigned short* __restrict__ H1, unsigned short* __restrict__ H1T)
{
  __shared__ unsigned short tile[64][72];
  int bid = blockIdx.x;
  int n = bid >> 3, kt = (bid >> 2) & 1, ht = bid & 3;
  int t = threadIdx.x;
  const unsigned short* src = H1 + (size_t)n * NCLS * HID + (size_t)(kt * 64) * HID + ht * 64;
#pragma unroll
  for (int j = 0; j < 2; ++j) {
    int u = j * 256 + t;
    int kk = u >> 3, h0 = (u & 7) * 8;
    *(frag*)&tile[kk][h0] = *(const frag*)(src + (size_t)kk * HID + h0);
  }
  __syncthreads();
  unsigned short* dst = H1T + (size_t)n * HID * NCLS + (size_t)(ht * 64) * NCLS + kt * 64;
#pragma unroll
  for (int j = 0; j < 2; ++j) {
    int u = j * 256 + t;
    int hh = u >> 3, k0 = (u & 7) * 8;
    frag v;
#pragma unroll
    for (int e = 0; e < 8; ++e) v[e] = (short)tile[k0 + e][hh];
    *(frag*)(dst + (size_t)hh * NCLS + k0) = v;
  }
}

// hs[c,i] += sum over n-chunk of H1
__global__ __launch_bounds__(256) void reduce_hs(
    const unsigned short* __restrict__ H1, float* __restrict__ hs)
{
  int bid = blockIdx.x;
  int c = bid >> 3, nch = bid & 7;
  int i = threadIdx.x;
  const unsigned short* p = H1 + (size_t)nch * 128 * NCLS * HID + (size_t)c * HID + i;
  float s = 0.f;
  for (int n = 0; n < 128; ++n) s += bf2f(p[(size_t)n * NCLS * HID]);
  atomicAdd(&hs[c * HID + i], s);
}

// hsW[k, col] col<1536 : sum_h hs[k,h] * w-half(col)[h]   (fp32)
__global__ __launch_bounds__(256) void p2a(
    const float* __restrict__ hs, const float* __restrict__ w3,
    const float* __restrict__ w4, const float* __restrict__ w5, float* __restrict__ hsW)
{
  __shared__ float hrow[HID];
  int k = blockIdx.x, t = threadIdx.x;
  hrow[t] = hs[k * HID + t];
  __syncthreads();
  for (int b = 0; b < 6; ++b) {
    int i = t;
    const float* w = (b < 2) ? w3 : (b < 4) ? w4 : w5;
    const float* row = w + (size_t)i * 512 + (b & 1) * 256;
    float s = 0.f;
    for (int h = 0; h < HID; ++h) s += hrow[h] * row[h];
    hsW[(size_t)k * 1536 + b * 256 + i] = s;
  }
}

// SG[c, g*256+i] = sum_k K[k,c]*hsW[k,2g,i] + K[c,k]*hsW[k,2g+1,i] + biases
__global__ __launch_bounds__(256) void p2b(
    const float* __restrict__ hsW, const float* __restrict__ Kn,
    const float* __restrict__ b3, const float* __restrict__ b4, const float* __restrict__ b5,
    const float* __restrict__ bu3, const float* __restrict__ bu5, float* __restrict__ SG)
{
  __shared__ float kc[NCLS], kr[NCLS];
  int c = blockIdx.x, t = threadIdx.x;
  if (t < NCLS) { kc[t] = Kn[t * NCLS + c]; kr[t] = Kn[c * NCLS + t]; }
  __syncthreads();
  for (int g = 0; g < 3; ++g) {
    int i = t;
    const float* L = hsW + (size_t)(2 * g) * 256 + i;
    const float* R = hsW + (size_t)(2 * g + 1) * 256 + i;
    float s = 0.f;
    for (int k = 0; k < NCLS; ++k) s += kc[k] * L[(size_t)k * 1536] + kr[k] * R[(size_t)k * 1536];
    const float* bg = (g == 0) ? b3 : (g == 1) ? b4 : b5;
    s += bg[i] + ((g < 2) ? bu3[i] : bu5[i]);
    SG[(size_t)c * 768 + g * 256 + i] = s;
  }
}

// layer-2 r gate: RH2 = sigmoid(SG4 + PRE4) * h1
__global__ __launch_bounds__(256) void e2_l2(
    const unsigned short* __restrict__ PRE, const float* __restrict__ SG,
    const unsigned short* __restrict__ H1, unsigned short* __restrict__ RH)
{
  int tid = blockIdx.x * 256 + threadIdx.x;
  int row = tid >> 5, i0 = (tid & 31) * 8;
  int c = row & 127;
  frag p4 = *(const frag*)(PRE + (size_t)row * 768 + 256 + i0);
  frag h1 = *(const frag*)(H1 + (size_t)row * HID + i0);
  const float* sg = SG + (size_t)c * 768 + 256;
  frag out;
#pragma unroll
  for (int e = 0; e < 8; ++e) {
    int i = i0 + e;
    float r = sigm(sg[i] + bf2f((unsigned short)p4[e]));
    out[e] = (short)f2bf(r * bf2f((unsigned short)h1[e]));
  }
  *(frag*)(RH + (size_t)row * HID + i0) = out;
}

// layer-2 final: out = (1-z)*h1 + z*tanh(SG5 + PRE5 + T2)
__global__ __launch_bounds__(256) void e3_l2(
    const unsigned short* __restrict__ PRE, const float* __restrict__ SG,
    const unsigned short* __restrict__ T2, const unsigned short* __restrict__ H1,
    float* __restrict__ out)
{
  int tid = blockIdx.x * 256 + threadIdx.x;
  int row = tid >> 5, i0 = (tid & 31) * 8;
  int c = row & 127;
  const unsigned short* pr = PRE + (size_t)row * 768;
  frag p3 = *(const frag*)(pr + i0);
  frag p5 = *(const frag*)(pr + 512 + i0);
  frag t2 = *(const frag*)(T2 + (size_t)row * HID + i0);
  frag h1 = *(const frag*)(H1 + (size_t)row * HID + i0);
  const float* sg = SG + (size_t)c * 768;
  float res[8];
#pragma unroll
  for (int e = 0; e < 8; ++e) {
    int i = i0 + e;
    float z  = sigm(sg[i] + bf2f((unsigned short)p3[e]));
    float pv = sg[512 + i] + bf2f((unsigned short)p5[e]) + bf2f((unsigned short)t2[e]);
    float hv = tanh_fast(pv);
    float h  = bf2f((unsigned short)h1[e]);
    res[e] = (1.0f - z) * h + z * hv;
  }
  f32x4 v0 = {res[0], res[1], res[2], res[3]};
  f32x4 v1 = {res[4], res[5], res[6], res[7]};
  *(f32x4*)(out + (size_t)row * HID + i0) = v0;
  *(f32x4*)(out + (size_t)row * HID + i0 + 4) = v1;
}

// ---------------------------------------------------------------------------
extern "C" void kernel_launch(void* const* d_in, const int* in_sizes, int n_in,
                              void* d_out, int out_size, void* d_ws, size_t ws_size,
                              hipStream_t stream) {
  (void)in_sizes; (void)n_in; (void)out_size; (void)ws_size;
  const float* x   = (const float*)d_in[0];
  const float* Kn  = (const float*)d_in[1];
  const float* w3  = (const float*)d_in[2];
  const float* b3  = (const float*)d_in[3];
  const float* u3  = (const float*)d_in[4];
  const float* bu3 = (const float*)d_in[5];
  const float* w4  = (const float*)d_in[6];
  const float* b4  = (const float*)d_in[7];
  const float* w5  = (const float*)d_in[8];
  const float* b5  = (const float*)d_in[9];
  const float* u5  = (const float*)d_in[10];
  const float* bu5 = (const float*)d_in[11];
  float* out = (float*)d_out;

  // workspace carve (bytes). Region X (128MiB) is time-shared:
  //   layer1: RH1(0:64M) + T1(64M:128M); nodeAB/G_PRE: AVH(0:128M);
  //   layer2: RH2(0:64M) + T2(64M:128M)
  char* w = (char*)d_ws;
  unsigned short* AVH = (unsigned short*)(w);
  unsigned short* RH  = (unsigned short*)(w);
  unsigned short* T   = (unsigned short*)(w + 67108864);
  unsigned short* PRE = (unsigned short*)(w + 134217728);
  unsigned short* H1  = (unsigned short*)(w + 335544320);
  unsigned short* H1T = (unsigned short*)(w + 402653184);
  float*          XW  = (float*)(w + 469762048);
  char* misc = w + 477102080;
  float* S      = (float*)(misc);
  float* hs     = (float*)(misc + 1024);
  float* SW     = (float*)(misc + 132096);
  float* colsum = (float*)(misc + 138240);
  float* rowsum = (float*)(misc + 138752);
  float* hsW    = (float*)(misc + 139264);
  float* SG     = (float*)(misc + 925696);
  unsigned short* WB   = (unsigned short*)(misc + 1318912);
  unsigned short* WB2  = (unsigned short*)(misc + 2498560);
  unsigned short* u5b  = (unsigned short*)(misc + 3416064);
  unsigned short* KbN  = (unsigned short*)(misc + 3547136);
  unsigned short* KTbN = (unsigned short*)(misc + 3579904);
  unsigned short* xb   = (unsigned short*)(misc + 3612672);

  hipMemsetAsync(misc, 0, 132096, stream);  // S + hs

  prep_cast<<<5504, 256, 0, stream>>>(x, Kn, w3, u3, w4, w5, u5, xb, WB, WB2, u5b, KbN, KTbN);
  prep_reduce<<<10, 256, 0, stream>>>(x, Kn, S, colsum, rowsum);
  prep_sw<<<6, 256, 0, stream>>>(S, w3, w4, w5, SW);

  // XW = x @ Wcat^T  [1024,256]x[256,1792] -> fp32
  gemm_bf16<0><<<8 * 14, 256, 0, stream>>>(xb, 256, 256, xb, 256, WB2, 256, 0L,
                                           (void*)XW, 1792, 14, 256, 0xFFFFFFFFu);
  e2_l1<<<16384, 256, 0, stream>>>(XW, SW, x, b4, bu3, colsum, rowsum, RH);
  // T1 = RH1 @ u5^T
  gemm_bf16<1><<<1024 * 2, 256, 0, stream>>>(RH, 256, 256, RH, 256, u5b, 256, 0L,
                                             (void*)T, 256, 2, 256, 0xFFFFFFFFu);
  e3_l1<<<16384, 256, 0, stream>>>(XW, SW, x, b3, bu3, b5, bu5, colsum, rowsum, T, H1);

  transpose_h1<<<8192, 256, 0, stream>>>(H1, H1T);
  reduce_hs<<<1024, 256, 0, stream>>>(H1, hs);
  p2a<<<128, 256, 0, stream>>>(hs, w3, w4, w5, hsW);
  p2b<<<128, 256, 0, stream>>>(hsW, Kn, b3, b4, b5, bu3, bu5, SG);

  // AVH[:,0:256] = -K^T Hid_n ; AVH[:,256:512] = -K Hid_n
  gemm_bf16<1><<<1024 * 2, 256, 0, stream>>>(KTbN, 128, 128, KTbN, 128, H1T, 128,
                                             (long)(HID * NCLS), (void*)AVH, 512, 2, 128, 127u);
  gemm_bf16<1><<<1024 * 2, 256, 0, stream>>>(KbN, 128, 128, KbN, 128, H1T, 128,
                                             (long)(HID * NCLS), (void*)(AVH + 256), 512, 2, 128, 127u);
  // PRE = [AVH | H1] @ WB   [131072,768]x[768,768]
  gemm_bf16<1><<<1024 * 6, 256, 0, stream>>>(AVH, 512, 512, H1, 256, WB, 768, 0L,
                                             (void*)PRE, 768, 6, 768, 0xFFFFFFFFu);
  e2_l2<<<16384, 256, 0, stream>>>(PRE, SG, H1, RH);
  // T2 = RH2 @ u5^T
  gemm_bf16<1><<<1024 * 2, 256, 0, stream>>>(RH, 256, 256, RH, 256, u5b, 256, 0L,
                                             (void*)T, 256, 2, 256, 0xFFFFFFFFu);
  e3_l2<<<16384, 256, 0, stream>>>(PRE, SG, T, H1, out);
}

// Round 2
// 861.193 us; speedup vs baseline: 1.0168x; 1.0168x over previous
//
#include <hip/hip_runtime.h>
#include <cstdint>
#include <cstddef>

// ---------------------------------------------------------------------------
// Graph_8564164788735: 2-layer class-conditioned GRU-ish propagation.
// N=1024 nodes, C=128 classes, H=256. Output fp32 [N,C,H].
//
// R2: XCD-swizzled GEMM grids (L2 reuse of A across n-tiles); layer-1 and
// layer-2 gate+update chains fused into the T=(r*h)@u5^T GEMMs (A on the
// fly, GRU update in epilogue, T kept fp32 in acc); transpose fused into
// layer-1 epilogue (writes H1 and H1T).
// ---------------------------------------------------------------------------

#define NODES 1024
#define NCLS  128
#define HID   256

using frag  = __attribute__((ext_vector_type(8))) short;
using frag4 = __attribute__((ext_vector_type(4))) short;
using f32x4 = __attribute__((ext_vector_type(4))) float;

__device__ __forceinline__ float bf2f(unsigned short h){
  unsigned int u = ((unsigned int)h) << 16;
  float f; __builtin_memcpy(&f, &u, 4); return f;
}
__device__ __forceinline__ unsigned short f2bf(float f){
  unsigned int u; __builtin_memcpy(&u, &f, 4);
  u = (u + 0x7fffu + ((u >> 16) & 1u)) >> 16;   // RNE
  return (unsigned short)u;
}
__device__ __forceinline__ float sigm(float x){ return 1.0f/(1.0f + __expf(-x)); }
__device__ __forceinline__ float tanh_fast(float x){ return 1.0f - 2.0f/(__expf(2.0f*x) + 1.0f); }

#define GLOBAL_AS(p) ((const __attribute__((address_space(1))) void*)(p))
#define LDS_AS(p)    ((__attribute__((address_space(3))) void*)(p))

// ---------------------------------------------------------------------------
// Generic bf16 MFMA GEMM, 128x128 tile, BK=32, 256 threads (4 waves, 2x2).
// XCD-swizzled: blocks sharing an m-tile land on the same XCD (bid%8) so the
// A-tile is L2-resident for all its n-tiles. Requires Mtiles%8==0 (or
// Mtiles<=8) and grid==Mtiles*Ntiles.
// C[row,col] = sum_k A(row,k) * BT[col,k]
// A(row,k): k <  K0 -> A0[(row & aMask)*ldA0 + k]
//           k >= K0 -> A1[row*ldA1 + (k-K0)]
// BT effective base = BT + mtile*bStride  (per-node batched B)
// ---------------------------------------------------------------------------
template<int OUT_BF16>
__global__ __launch_bounds__(256) void gemm_bf16(
    const unsigned short* __restrict__ A0, int ldA0, int K0,
    const unsigned short* __restrict__ A1, int ldA1,
    const unsigned short* __restrict__ BT, int ldB, long bStride,
    void* __restrict__ Cptr, int ldC,
    int Ntiles, int Ktot, unsigned int aMask, int Mtiles)
{
  __shared__ unsigned short As[4096];   // [128 m][32 k]
  __shared__ unsigned short Bs[4096];   // [128 n][32 k]
  const int t   = threadIdx.x;
  const int bid = blockIdx.x;
  const int xcd = bid & 7, slot = bid >> 3;
  const int mtPerX = (Mtiles >= 8) ? (Mtiles >> 3) : 1;
  const int mt = xcd * mtPerX + slot / Ntiles;
  const int nt = slot % Ntiles;
  const int lane = t & 63, w = t >> 6;
  const int wm = w >> 1, wn = w & 1;
  const int r = lane & 15, q = lane >> 4;
  const int m0 = mt * 128, n0 = nt * 128;
  const unsigned short* Bbase = BT + (size_t)mt * (size_t)bStride;

  f32x4 acc[4][4] = {};

  for (int kb = 0; kb < Ktot; kb += 32) {
#pragma unroll
    for (int i = 0; i < 2; ++i) {
      int u  = i * 256 + t;
      int mi = u >> 2;
      int kc = (u & 3) * 8;
      int k  = kb + kc;
      const unsigned short* ga;
      if (k < K0) ga = A0 + (size_t)((unsigned int)(m0 + mi) & aMask) * (size_t)ldA0 + k;
      else        ga = A1 + (size_t)(m0 + mi) * (size_t)ldA1 + (k - K0);
      __builtin_amdgcn_global_load_lds(GLOBAL_AS(ga), LDS_AS(&As[u * 8]), 16, 0, 0);
      const unsigned short* gb = Bbase + (size_t)(n0 + mi) * (size_t)ldB + k;
      __builtin_amdgcn_global_load_lds(GLOBAL_AS(gb), LDS_AS(&Bs[u * 8]), 16, 0, 0);
    }
    __syncthreads();

    frag af[4], bf_[4];
#pragma unroll
    for (int x = 0; x < 4; ++x) {
      af[x]  = *(const frag*)&As[(wm * 64 + x * 16 + r) * 32 + q * 8];
      bf_[x] = *(const frag*)&Bs[(wn * 64 + x * 16 + r) * 32 + q * 8];
    }
#pragma unroll
    for (int x = 0; x < 4; ++x)
#pragma unroll
      for (int y = 0; y < 4; ++y)
        acc[x][y] = __builtin_amdgcn_mfma_f32_16x16x32_bf16(af[x], bf_[y], acc[x][y], 0, 0, 0);
    __syncthreads();
  }

#pragma unroll
  for (int x = 0; x < 4; ++x) {
#pragma unroll
    for (int y = 0; y < 4; ++y) {
      int col = n0 + wn * 64 + y * 16 + r;
#pragma unroll
      for (int g = 0; g < 4; ++g) {
        long row = m0 + wm * 64 + x * 16 + q * 4 + g;
        if (OUT_BF16) ((unsigned short*)Cptr)[row * (long)ldC + col] = f2bf(acc[x][y][g]);
        else          ((float*)Cptr)[row * (long)ldC + col] = acc[x][y][g];
      }
    }
  }
}

// ---------------------------------------------------------------------------
// Fused layer-1: T1 = (sigm(pre4) * x_n) @ u5^T with the GRU update in the
// epilogue; writes H1 and H1T. One m-tile == one node (128 class rows).
// All gate pre-activations have the form cs*P1[i] + rs*P2[i] + P3[i] with
// per-node tables -> precompute into LDS in a prologue.
// Mtiles=1024, Ntiles=2 (hidden halves), grid 2048.
// ---------------------------------------------------------------------------
__global__ __launch_bounds__(256) void gemm_l1(
    const float* __restrict__ XW, const float* __restrict__ SW,
    const float* __restrict__ x,
    const float* __restrict__ b3, const float* __restrict__ b4,
    const float* __restrict__ b5, const float* __restrict__ bu3,
    const float* __restrict__ bu5,
    const float* __restrict__ colsum, const float* __restrict__ rowsum,
    const unsigned short* __restrict__ u5b,
    unsigned short* __restrict__ H1, unsigned short* __restrict__ H1T)
{
  __shared__ unsigned short As[4096], Bs[4096];
  __shared__ float tP1[256], tP2[256], tP3[256], tX[256];
  __shared__ float tZ1[256], tZ2[256], tZ3[256];
  __shared__ float tV1[256], tV2[256], tV3[256];
  __shared__ float tCS[128], tRS[128];

  const int t = threadIdx.x, bid = blockIdx.x;
  const int xcd = bid & 7, slot = bid >> 3;
  const int n  = xcd * 128 + (slot >> 1);   // node = m-tile
  const int nt = slot & 1;
  const int lane = t & 63, w = t >> 6, wm = w >> 1, wn = w & 1;
  const int r = lane & 15, q = lane >> 4;
  const int n0 = nt * 128;
  const float* xw = XW + (size_t)n * 1792;

  { // prologue: per-node gate tables
    int i = t;
    float xwi0 = xw[i], xwi1 = xw[256 + i], xwi2 = xw[512 + i], xwi3 = xw[768 + i];
    float xwi4 = xw[1024 + i], xwi5 = xw[1280 + i], xwu = xw[1536 + i];
    tP1[i] = SW[512 + i] - xwi2;
    tP2[i] = SW[768 + i] - xwi3;
    tP3[i] = xwu + b4[i] + bu3[i];
    tX[i]  = x[(size_t)n * HID + i];
    tZ1[i] = SW[i] - xwi0;
    tZ2[i] = SW[256 + i] - xwi1;
    tZ3[i] = xwu + b3[i] + bu3[i];
    tV1[i] = SW[1024 + i] - xwi4;
    tV2[i] = SW[1280 + i] - xwi5;
    tV3[i] = b5[i] + bu5[i];
    if (t < 128) { tCS[t] = colsum[t]; tRS[t] = rowsum[t]; }
  }
  __syncthreads();

  f32x4 acc[4][4] = {};

  for (int kb = 0; kb < 256; kb += 32) {
#pragma unroll
    for (int i = 0; i < 2; ++i) {
      int u  = i * 256 + t;
      int mi = u >> 2;                 // class row
      int kc = (u & 3) * 8;
      int k  = kb + kc;
      __builtin_amdgcn_global_load_lds(GLOBAL_AS(u5b + (size_t)(n0 + mi) * 256 + k),
                                       LDS_AS(&Bs[u * 8]), 16, 0, 0);
      float cs = tCS[mi], rs = tRS[mi];
      frag a;
#pragma unroll
      for (int e = 0; e < 8; ++e) {
        int i2 = k + e;
        float pre = cs * tP1[i2] + rs * tP2[i2] + tP3[i2];
        a[e] = (short)f2bf(sigm(pre) * tX[i2]);
      }
      *(frag*)&As[u * 8] = a;
    }
    __syncthreads();

    frag af[4], bf_[4];
#pragma unroll
    for (int xx = 0; xx < 4; ++xx) {
      af[xx]  = *(const frag*)&As[(wm * 64 + xx * 16 + r) * 32 + q * 8];
      bf_[xx] = *(const frag*)&Bs[(wn * 64 + xx * 16 + r) * 32 + q * 8];
    }
#pragma unroll
    for (int xx = 0; xx < 4; ++xx)
#pragma unroll
      for (int y = 0; y < 4; ++y)
        acc[xx][y] = __builtin_amdgcn_mfma_f32_16x16x32_bf16(af[xx], bf_[y], acc[xx][y], 0, 0, 0);
    __syncthreads();
  }

  // epilogue: GRU update, write H1 [row][i] and H1T [n][i][c]
#pragma unroll
  for (int xx = 0; xx < 4; ++xx) {
#pragma unroll
    for (int y = 0; y < 4; ++y) {
      int i = n0 + wn * 64 + y * 16 + r;          // hidden col
      frag4 pack;
#pragma unroll
      for (int g = 0; g < 4; ++g) {
        int c = wm * 64 + xx * 16 + q * 4 + g;    // class row
        float cs = tCS[c], rs = tRS[c];
        float z  = sigm(cs * tZ1[i] + rs * tZ2[i] + tZ3[i]);
        float p5 = cs * tV1[i] + rs * tV2[i] + tV3[i] + acc[xx][y][g];
        float h1 = (1.0f - z) * tX[i] + z * tanh_fast(p5);
        unsigned short hb = f2bf(h1);
        pack[g] = (short)hb;
        H1[(size_t)(n * 128 + c) * HID + i] = hb;
      }
      *(frag4*)(H1T + (size_t)n * (HID * NCLS) + (size_t)i * NCLS
                + (wm * 64 + xx * 16 + q * 4)) = pack;
    }
  }
}

// ---------------------------------------------------------------------------
// Fused layer-2: T2 = (sigm(SG4+PRE4) * h1) @ u5^T ; epilogue does the GRU
// update and writes the fp32 output. Mtiles=1024, Ntiles=2, grid 2048.
// ---------------------------------------------------------------------------
__global__ __launch_bounds__(256) void gemm_l2(
    const unsigned short* __restrict__ PRE, const float* __restrict__ SG,
    const unsigned short* __restrict__ H1, const unsigned short* __restrict__ u5b,
    float* __restrict__ out)
{
  __shared__ unsigned short As[4096], Bs[4096];
  const int t = threadIdx.x, bid = blockIdx.x;
  const int xcd = bid & 7, slot = bid >> 3;
  const int mt = xcd * 128 + (slot >> 1);
  const int nt = slot & 1;
  const int lane = t & 63, w = t >> 6, wm = w >> 1, wn = w & 1;
  const int r = lane & 15, q = lane >> 4;
  const int m0 = mt * 128, n0 = nt * 128;

  f32x4 acc[4][4] = {};

  for (int kb = 0; kb < 256; kb += 32) {
#pragma unroll
    for (int i = 0; i < 2; ++i) {
      int u  = i * 256 + t;
      int mi = u >> 2;                 // class row
      int kc = (u & 3) * 8;
      int k  = kb + kc;
      __builtin_amdgcn_global_load_lds(GLOBAL_AS(u5b + (size_t)(n0 + mi) * 256 + k),
                                       LDS_AS(&Bs[u * 8]), 16, 0, 0);
      long row = m0 + mi;
      frag p4 = *(const frag*)(PRE + row * 768 + 256 + k);
      frag h1 = *(const frag*)(H1 + row * 256 + k);
      const float* sg = SG + (size_t)mi * 768 + 256 + k;
      frag a;
#pragma unroll
      for (int e = 0; e < 8; ++e) {
        float rv = sigm(sg[e] + bf2f((unsigned short)p4[e]));
        a[e] = (short)f2bf(rv * bf2f((unsigned short)h1[e]));
      }
      *(frag*)&As[u * 8] = a;
    }
    __syncthreads();

    frag af[4], bf_[4];
#pragma unroll
    for (int xx = 0; xx < 4; ++xx) {
      af[xx]  = *(const frag*)&As[(wm * 64 + xx * 16 + r) * 32 + q * 8];
      bf_[xx] = *(const frag*)&Bs[(wn * 64 + xx * 16 + r) * 32 + q * 8];
    }
#pragma unroll
    for (int xx = 0; xx < 4; ++xx)
#pragma unroll
      for (int y = 0; y < 4; ++y)
        acc[xx][y] = __builtin_amdgcn_mfma_f32_16x16x32_bf16(af[xx], bf_[y], acc[xx][y], 0, 0, 0);
    __syncthreads();
  }

#pragma unroll
  for (int xx = 0; xx < 4; ++xx) {
#pragma unroll
    for (int y = 0; y < 4; ++y) {
      int i = n0 + wn * 64 + y * 16 + r;          // hidden col
#pragma unroll
      for (int g = 0; g < 4; ++g) {
        int c = wm * 64 + xx * 16 + q * 4 + g;
        long row = m0 + c;
        float z  = sigm(SG[(size_t)c * 768 + i] + bf2f(PRE[row * 768 + i]));
        float pv = SG[(size_t)c * 768 + 512 + i] + bf2f(PRE[row * 768 + 512 + i])
                 + acc[xx][y][g];
        float h  = bf2f(H1[row * 256 + i]);
        out[row * 256 + i] = (1.0f - z) * h + z * tanh_fast(pv);
      }
    }
  }
}

// ---------------------------------------------------------------------------
// prep: bf16 casts + weight repacks (unchanged from R1).
// ---------------------------------------------------------------------------
__global__ __launch_bounds__(256) void prep_cast(
    const float* __restrict__ x, const float* __restrict__ Kn,
    const float* __restrict__ w3, const float* __restrict__ u3,
    const float* __restrict__ w4, const float* __restrict__ w5,
    const float* __restrict__ u5,
    unsigned short* __restrict__ xb, unsigned short* __restrict__ WB,
    unsigned short* __restrict__ WB2, unsigned short* __restrict__ u5b,
    unsigned short* __restrict__ KbN, unsigned short* __restrict__ KTbN)
{
  int idx = blockIdx.x * 256 + threadIdx.x;
  if (idx < 262144) { xb[idx] = f2bf(x[idx]); return; }
  idx -= 262144;
  if (idx < 589824) {
    int col = idx / 768, j = idx % 768;
    int g = col >> 8, i = col & 255;
    float v;
    if (j < 512) { const float* wg = (g == 0) ? w3 : (g == 1) ? w4 : w5; v = wg[(size_t)i * 512 + j]; }
    else v = (g < 2) ? u3[(size_t)i * 256 + (j - 512)] : 0.0f;
    WB[(size_t)col * 768 + j] = f2bf(v);
    return;
  }
  idx -= 589824;
  if (idx < 458752) {
    int col = idx / 256, h = idx % 256;
    int b = col >> 8, i = col & 255;
    float v = (b < 6) ? ((b < 2 ? w3 : (b < 4 ? w4 : w5))[(size_t)i * 512 + (b & 1) * 256 + h])
                      : u3[(size_t)i * 256 + h];
    WB2[(size_t)col * 256 + h] = f2bf(v);
    return;
  }
  idx -= 458752;
  if (idx < 65536) { u5b[idx] = f2bf(u5[idx]); return; }
  idx -= 65536;
  if (idx < 16384) { int c = idx >> 7, k = idx & 127; KbN[idx]  = f2bf(-Kn[c * 128 + k]); return; }
  idx -= 16384;
  { int c = idx >> 7, k = idx & 127; KTbN[idx] = f2bf(-Kn[k * 128 + c]); }
}

__global__ __launch_bounds__(256) void prep_reduce(
    const float* __restrict__ x, const float* __restrict__ Kn,
    float* __restrict__ S, float* __restrict__ colsum, float* __restrict__ rowsum)
{
  int b = blockIdx.x, t = threadIdx.x;
  if (b < 8) {
    float s = 0.f;
    for (int n = 0; n < 128; ++n) s += x[(size_t)(b * 128 + n) * HID + t];
    atomicAdd(&S[t], s);
  } else if (b == 8) {
    if (t < NCLS) { float s = 0.f; for (int k = 0; k < NCLS; ++k) s += Kn[k * NCLS + t]; colsum[t] = s; }
  } else {
    if (t < NCLS) { float s = 0.f; for (int k = 0; k < NCLS; ++k) s += Kn[t * NCLS + k]; rowsum[t] = s; }
  }
}

__global__ __launch_bounds__(256) void prep_sw(
    const float* __restrict__ S, const float* __restrict__ w3,
    const float* __restrict__ w4, const float* __restrict__ w5, float* __restrict__ SW)
{
  int col = blockIdx.x * 256 + threadIdx.x;
  int b = col >> 8, i = col & 255;
  const float* w = (b < 2) ? w3 : (b < 4) ? w4 : w5;
  const float* row = w + (size_t)i * 512 + (b & 1) * 256;
  float s = 0.f;
  for (int h = 0; h < HID; ++h) s += S[h] * row[h];
  SW[col] = s;
}

__global__ __launch_bounds__(256) void reduce_hs(
    const unsigned short* __restrict__ H1, float* __restrict__ hs)
{
  int bid = blockIdx.x;
  int c = bid >> 3, nch = bid & 7;
  int i = threadIdx.x;
  const unsigned short* p = H1 + (size_t)nch * 128 * NCLS * HID + (size_t)c * HID + i;
  float s = 0.f;
  for (int n = 0; n < 128; ++n) s += bf2f(p[(size_t)n * NCLS * HID]);
  atomicAdd(&hs[c * HID + i], s);
}

__global__ __launch_bounds__(256) void p2a(
    const float* __restrict__ hs, const float* __restrict__ w3,
    const float* __restrict__ w4, const float* __restrict__ w5, float* __restrict__ hsW)
{
  __shared__ float hrow[HID];
  int k = blockIdx.x, t = threadIdx.x;
  hrow[t] = hs[k * HID + t];
  __syncthreads();
  for (int b = 0; b < 6; ++b) {
    int i = t;
    const float* w = (b < 2) ? w3 : (b < 4) ? w4 : w5;
    const float* row = w + (size_t)i * 512 + (b & 1) * 256;
    float s = 0.f;
    for (int h = 0; h < HID; ++h) s += hrow[h] * row[h];
    hsW[(size_t)k * 1536 + b * 256 + i] = s;
  }
}

__global__ __launch_bounds__(256) void p2b(
    const float* __restrict__ hsW, const float* __restrict__ Kn,
    const float* __restrict__ b3, const float* __restrict__ b4, const float* __restrict__ b5,
    const float* __restrict__ bu3, const float* __restrict__ bu5, float* __restrict__ SG)
{
  __shared__ float kc[NCLS], kr[NCLS];
  int c = blockIdx.x, t = threadIdx.x;
  if (t < NCLS) { kc[t] = Kn[t * NCLS + c]; kr[t] = Kn[c * NCLS + t]; }
  __syncthreads();
  for (int g = 0; g < 3; ++g) {
    int i = t;
    const float* L = hsW + (size_t)(2 * g) * 256 + i;
    const float* R = hsW + (size_t)(2 * g + 1) * 256 + i;
    float s = 0.f;
    for (int k = 0; k < NCLS; ++k) s += kc[k] * L[(size_t)k * 1536] + kr[k] * R[(size_t)k * 1536];
    const float* bg = (g == 0) ? b3 : (g == 1) ? b4 : b5;
    s += bg[i] + ((g < 2) ? bu3[i] : bu5[i]);
    SG[(size_t)c * 768 + g * 256 + i] = s;
  }
}

// ---------------------------------------------------------------------------
extern "C" void kernel_launch(void* const* d_in, const int* in_sizes, int n_in,
                              void* d_out, int out_size, void* d_ws, size_t ws_size,
                              hipStream_t stream) {
  (void)in_sizes; (void)n_in; (void)out_size; (void)ws_size;
  const float* x   = (const float*)d_in[0];
  const float* Kn  = (const float*)d_in[1];
  const float* w3  = (const float*)d_in[2];
  const float* b3  = (const float*)d_in[3];
  const float* u3  = (const float*)d_in[4];
  const float* bu3 = (const float*)d_in[5];
  const float* w4  = (const float*)d_in[6];
  const float* b4  = (const float*)d_in[7];
  const float* w5  = (const float*)d_in[8];
  const float* b5  = (const float*)d_in[9];
  const float* u5  = (const float*)d_in[10];
  const float* bu5 = (const float*)d_in[11];
  float* out = (float*)d_out;

  char* w = (char*)d_ws;
  unsigned short* AVH = (unsigned short*)(w);                 // 131072x512 bf16 (128 MiB)
  unsigned short* PRE = (unsigned short*)(w + 134217728);     // 131072x768 bf16 (192 MiB)
  unsigned short* H1  = (unsigned short*)(w + 335544320);     // 131072x256 bf16 (64 MiB)
  unsigned short* H1T = (unsigned short*)(w + 402653184);     // per-node transposed (64 MiB)
  float*          XW  = (float*)(w + 469762048);              // 1024x1792 fp32
  char* misc = w + 477102080;
  float* S      = (float*)(misc);
  float* hs     = (float*)(misc + 1024);
  float* SW     = (float*)(misc + 132096);
  float* colsum = (float*)(misc + 138240);
  float* rowsum = (float*)(misc + 138752);
  float* hsW    = (float*)(misc + 139264);
  float* SG     = (float*)(misc + 925696);
  unsigned short* WB   = (unsigned short*)(misc + 1318912);
  unsigned short* WB2  = (unsigned short*)(misc + 2498560);
  unsigned short* u5b  = (unsigned short*)(misc + 3416064);
  unsigned short* KbN  = (unsigned short*)(misc + 3547136);
  unsigned short* KTbN = (unsigned short*)(misc + 3579904);
  unsigned short* xb   = (unsigned short*)(misc + 3612672);

  hipMemsetAsync(misc, 0, 132096, stream);  // S + hs

  prep_cast<<<5504, 256, 0, stream>>>(x, Kn, w3, u3, w4, w5, u5, xb, WB, WB2, u5b, KbN, KTbN);
  prep_reduce<<<10, 256, 0, stream>>>(x, Kn, S, colsum, rowsum);
  prep_sw<<<6, 256, 0, stream>>>(S, w3, w4, w5, SW);

  // XW = x @ Wcat^T  [1024,256]x[256,1792] -> fp32
  gemm_bf16<0><<<8 * 14, 256, 0, stream>>>(xb, 256, 256, xb, 256, WB2, 256, 0L,
                                           (void*)XW, 1792, 14, 256, 0xFFFFFFFFu, 8);
  // fused layer 1 -> H1, H1T
  gemm_l1<<<2048, 256, 0, stream>>>(XW, SW, x, b3, b4, b5, bu3, bu5,
                                    colsum, rowsum, u5b, H1, H1T);

  reduce_hs<<<1024, 256, 0, stream>>>(H1, hs);
  p2a<<<128, 256, 0, stream>>>(hs, w3, w4, w5, hsW);
  p2b<<<128, 256, 0, stream>>>(hsW, Kn, b3, b4, b5, bu3, bu5, SG);

  // AVH[:,0:256] = -K^T Hid_n ; AVH[:,256:512] = -K Hid_n
  gemm_bf16<1><<<1024 * 2, 256, 0, stream>>>(KTbN, 128, 128, KTbN, 128, H1T, 128,
                                             (long)(HID * NCLS), (void*)AVH, 512, 2, 128, 127u, 1024);
  gemm_bf16<1><<<1024 * 2, 256, 0, stream>>>(KbN, 128, 128, KbN, 128, H1T, 128,
                                             (long)(HID * NCLS), (void*)(AVH + 256), 512, 2, 128, 127u, 1024);
  // PRE = [AVH | H1] @ WB   [131072,768]x[768,768]
  gemm_bf16<1><<<1024 * 6, 256, 0, stream>>>(AVH, 512, 512, H1, 256, WB, 768, 0L,
                                             (void*)PRE, 768, 6, 768, 0xFFFFFFFFu, 1024);
  // fused layer 2 -> out
  gemm_l2<<<2048, 256, 0, stream>>>(PRE, SG, H1, u5b, out);
}

// Round 3
// 836.664 us; speedup vs baseline: 1.0466x; 1.0293x over previous
//
#include <hip/hip_runtime.h>
#include <cstdint>
#include <cstddef>

// ---------------------------------------------------------------------------
// Graph_8564164788735: 2-layer class-conditioned GRU-ish propagation.
// N=1024 nodes, C=128 classes, H=256. Output fp32 [N,C,H].
//
// R3: per-node fused gemm_node replaces AVH GEMMs + PRE GEMM:
//   stage1: Q_n = [-K^T H_n | -K H_n]  (MFMA -> LDS, 128x512 bf16, swizzled)
//   stage2: PRE_n = [Q_n | H_n] @ WB   (A from LDS; w5 zero-block skipped)
// Kills the 256 MB AVH HBM round-trip and the two K=128 epilogue-heavy GEMMs.
// ---------------------------------------------------------------------------

#define NODES 1024
#define NCLS  128
#define HID   256

using frag  = __attribute__((ext_vector_type(8))) short;
using frag4 = __attribute__((ext_vector_type(4))) short;
using f32x4 = __attribute__((ext_vector_type(4))) float;

__device__ __forceinline__ float bf2f(unsigned short h){
  unsigned int u = ((unsigned int)h) << 16;
  float f; __builtin_memcpy(&f, &u, 4); return f;
}
__device__ __forceinline__ unsigned short f2bf(float f){
  unsigned int u; __builtin_memcpy(&u, &f, 4);
  u = (u + 0x7fffu + ((u >> 16) & 1u)) >> 16;   // RNE
  return (unsigned short)u;
}
__device__ __forceinline__ float sigm(float x){ return 1.0f/(1.0f + __expf(-x)); }
__device__ __forceinline__ float tanh_fast(float x){ return 1.0f - 2.0f/(__expf(2.0f*x) + 1.0f); }

#define GLOBAL_AS(p) ((const __attribute__((address_space(1))) void*)(p))
#define LDS_AS(p)    ((__attribute__((address_space(3))) void*)(p))

// ---------------------------------------------------------------------------
// Generic bf16 MFMA GEMM (now only used for XW). 128x128 tile, BK=32.
// ---------------------------------------------------------------------------
template<int OUT_BF16>
__global__ __launch_bounds__(256) void gemm_bf16(
    const unsigned short* __restrict__ A0, int ldA0, int K0,
    const unsigned short* __restrict__ A1, int ldA1,
    const unsigned short* __restrict__ BT, int ldB, long bStride,
    void* __restrict__ Cptr, int ldC,
    int Ntiles, int Ktot, unsigned int aMask, int Mtiles)
{
  __shared__ unsigned short As[4096];
  __shared__ unsigned short Bs[4096];
  const int t   = threadIdx.x;
  const int bid = blockIdx.x;
  const int xcd = bid & 7, slot = bid >> 3;
  const int mtPerX = (Mtiles >= 8) ? (Mtiles >> 3) : 1;
  const int mt = xcd * mtPerX + slot / Ntiles;
  const int nt = slot % Ntiles;
  const int lane = t & 63, w = t >> 6;
  const int wm = w >> 1, wn = w & 1;
  const int r = lane & 15, q = lane >> 4;
  const int m0 = mt * 128, n0 = nt * 128;
  const unsigned short* Bbase = BT + (size_t)mt * (size_t)bStride;

  f32x4 acc[4][4] = {};

  for (int kb = 0; kb < Ktot; kb += 32) {
#pragma unroll
    for (int i = 0; i < 2; ++i) {
      int u  = i * 256 + t;
      int mi = u >> 2;
      int kc = (u & 3) * 8;
      int k  = kb + kc;
      const unsigned short* ga;
      if (k < K0) ga = A0 + (size_t)((unsigned int)(m0 + mi) & aMask) * (size_t)ldA0 + k;
      else        ga = A1 + (size_t)(m0 + mi) * (size_t)ldA1 + (k - K0);
      __builtin_amdgcn_global_load_lds(GLOBAL_AS(ga), LDS_AS(&As[u * 8]), 16, 0, 0);
      const unsigned short* gb = Bbase + (size_t)(n0 + mi) * (size_t)ldB + k;
      __builtin_amdgcn_global_load_lds(GLOBAL_AS(gb), LDS_AS(&Bs[u * 8]), 16, 0, 0);
    }
    __syncthreads();

    frag af[4], bf_[4];
#pragma unroll
    for (int x = 0; x < 4; ++x) {
      af[x]  = *(const frag*)&As[(wm * 64 + x * 16 + r) * 32 + q * 8];
      bf_[x] = *(const frag*)&Bs[(wn * 64 + x * 16 + r) * 32 + q * 8];
    }
#pragma unroll
    for (int x = 0; x < 4; ++x)
#pragma unroll
      for (int y = 0; y < 4; ++y)
        acc[x][y] = __builtin_amdgcn_mfma_f32_16x16x32_bf16(af[x], bf_[y], acc[x][y], 0, 0, 0);
    __syncthreads();
  }

#pragma unroll
  for (int x = 0; x < 4; ++x) {
#pragma unroll
    for (int y = 0; y < 4; ++y) {
      int col = n0 + wn * 64 + y * 16 + r;
#pragma unroll
      for (int g = 0; g < 4; ++g) {
        long row = m0 + wm * 64 + x * 16 + q * 4 + g;
        if (OUT_BF16) ((unsigned short*)Cptr)[row * (long)ldC + col] = f2bf(acc[x][y][g]);
        else          ((float*)Cptr)[row * (long)ldC + col] = acc[x][y][g];
      }
    }
  }
}

// ---------------------------------------------------------------------------
// gemm_node: per-node fused  Q = [-K^T H_n | -K H_n]  then  PRE_n = [Q|H_n]@WB
// grid 1024 (XCD-swizzled), 512 threads (2 groups x 4 waves), 160 KiB LDS.
// Q lives in LDS as bf16 with k-block XOR swizzle (jblk ^= c&7) so stage-2
// A-frag ds_read_b128 is ~conflict-free.
// ---------------------------------------------------------------------------
__global__ __launch_bounds__(512) void gemm_node(
    const unsigned short* __restrict__ KTbN, const unsigned short* __restrict__ KbN,
    const unsigned short* __restrict__ H1T, const unsigned short* __restrict__ H1,
    const unsigned short* __restrict__ WB, unsigned short* __restrict__ PRE)
{
  __shared__ unsigned short Qs[128 * 512];   // 128 KiB
  __shared__ unsigned short As[2][4096];     // 16 KiB
  __shared__ unsigned short Bs[2][4096];     // 16 KiB

  const int t   = threadIdx.x;
  const int bid = blockIdx.x;
  const int node = (bid & 7) * 128 + (bid >> 3);
  const int g  = t >> 8;            // group 0/1
  const int tg = t & 255;
  const int w  = t >> 6;
  const int wl = w & 3;
  const int wm = wl >> 1, wn = wl & 1;
  const int lane = t & 63;
  const int r = lane & 15, q = lane >> 4;

  f32x4 acc[4][4];

  // ---------------- stage 1: Q into LDS ----------------
  const unsigned short* Ksrc = g ? KbN : KTbN;
  for (int hh = 0; hh < 2; ++hh) {
#pragma unroll
    for (int x = 0; x < 4; ++x)
#pragma unroll
      for (int y = 0; y < 4; ++y) acc[x][y] = (f32x4){0.f, 0.f, 0.f, 0.f};

    for (int kb = 0; kb < 128; kb += 32) {
#pragma unroll
      for (int i = 0; i < 2; ++i) {
        int u = i * 256 + tg;
        int mi = u >> 2, kc = (u & 3) * 8;
        __builtin_amdgcn_global_load_lds(GLOBAL_AS(Ksrc + (size_t)mi * 128 + kb + kc),
                                         LDS_AS(&As[g][u * 8]), 16, 0, 0);
      }
      {
        int mi = t >> 2, kc = (t & 3) * 8;
        __builtin_amdgcn_global_load_lds(GLOBAL_AS(H1T + (size_t)node * (HID * NCLS)
                                           + (size_t)(hh * 128 + mi) * 128 + kb + kc),
                                         LDS_AS(&Bs[0][t * 8]), 16, 0, 0);
      }
      __syncthreads();

      frag af[4], bf_[4];
#pragma unroll
      for (int x = 0; x < 4; ++x) {
        af[x]  = *(const frag*)&As[g][(wm * 64 + x * 16 + r) * 32 + q * 8];
        bf_[x] = *(const frag*)&Bs[0][(wn * 64 + x * 16 + r) * 32 + q * 8];
      }
#pragma unroll
      for (int x = 0; x < 4; ++x)
#pragma unroll
        for (int y = 0; y < 4; ++y)
          acc[x][y] = __builtin_amdgcn_mfma_f32_16x16x32_bf16(af[x], bf_[y], acc[x][y], 0, 0, 0);
      __syncthreads();
    }

    // epilogue -> Qs (swizzled scalar bf16 writes)
    int jBase = g * 256 + hh * 128;
#pragma unroll
    for (int x = 0; x < 4; ++x)
#pragma unroll
      for (int y = 0; y < 4; ++y)
#pragma unroll
        for (int gg = 0; gg < 4; ++gg) {
          int c = wm * 64 + x * 16 + q * 4 + gg;
          int j = jBase + wn * 64 + y * 16 + r;
          int jblk = (j >> 3) ^ (c & 7);
          Qs[c * 512 + jblk * 8 + (j & 7)] = f2bf(acc[x][y][gg]);
        }
  }
  __syncthreads();

  // ---------------- stage 2: PRE_n = [Q | H_n] @ WB ----------------
  for (int rd = 0; rd < 3; ++rd) {
    const int ct = rd * 2 + g;                 // col-tile (gate = ct>>1)
    const int kmax = (rd < 2) ? 768 : 512;     // w5 u3-block is zero
#pragma unroll
    for (int x = 0; x < 4; ++x)
#pragma unroll
      for (int y = 0; y < 4; ++y) acc[x][y] = (f32x4){0.f, 0.f, 0.f, 0.f};

    for (int kb = 0; kb < kmax; kb += 32) {
#pragma unroll
      for (int i = 0; i < 2; ++i) {
        int u = i * 256 + tg;
        int mi = u >> 2, kc = (u & 3) * 8;
        __builtin_amdgcn_global_load_lds(GLOBAL_AS(WB + (size_t)(ct * 128 + mi) * 768 + kb + kc),
                                         LDS_AS(&Bs[g][u * 8]), 16, 0, 0);
      }
      if (kb >= 512) {
        int mi = t >> 2, kc = (t & 3) * 8;
        __builtin_amdgcn_global_load_lds(GLOBAL_AS(H1 + (size_t)(node * 128 + mi) * 256
                                           + (kb - 512) + kc),
                                         LDS_AS(&As[0][t * 8]), 16, 0, 0);
      }
      __syncthreads();

      frag af[4], bf_[4];
      if (kb < 512) {
        int jb0 = (kb >> 3) + q;
#pragma unroll
        for (int x = 0; x < 4; ++x) {
          int c = wm * 64 + x * 16 + r;
          int jblk = jb0 ^ (c & 7);
          af[x] = *(const frag*)&Qs[c * 512 + jblk * 8];
        }
      } else {
#pragma unroll
        for (int x = 0; x < 4; ++x)
          af[x] = *(const frag*)&As[0][(wm * 64 + x * 16 + r) * 32 + q * 8];
      }
#pragma unroll
      for (int y = 0; y < 4; ++y)
        bf_[y] = *(const frag*)&Bs[g][(wn * 64 + y * 16 + r) * 32 + q * 8];
#pragma unroll
      for (int x = 0; x < 4; ++x)
#pragma unroll
        for (int y = 0; y < 4; ++y)
          acc[x][y] = __builtin_amdgcn_mfma_f32_16x16x32_bf16(af[x], bf_[y], acc[x][y], 0, 0, 0);
      __syncthreads();
    }

    // epilogue -> PRE
#pragma unroll
    for (int x = 0; x < 4; ++x)
#pragma unroll
      for (int y = 0; y < 4; ++y) {
        int lc = wn * 64 + y * 16 + r;
#pragma unroll
        for (int gg = 0; gg < 4; ++gg) {
          int c = wm * 64 + x * 16 + q * 4 + gg;
          PRE[(size_t)(node * 128 + c) * 768 + ct * 128 + lc] = f2bf(acc[x][y][gg]);
        }
      }
  }
}

// ---------------------------------------------------------------------------
// Fused layer-1 (unchanged from R2): T1 GEMM + GRU update; writes H1 and H1T.
// ---------------------------------------------------------------------------
__global__ __launch_bounds__(256) void gemm_l1(
    const float* __restrict__ XW, const float* __restrict__ SW,
    const float* __restrict__ x,
    const float* __restrict__ b3, const float* __restrict__ b4,
    const float* __restrict__ b5, const float* __restrict__ bu3,
    const float* __restrict__ bu5,
    const float* __restrict__ colsum, const float* __restrict__ rowsum,
    const unsigned short* __restrict__ u5b,
    unsigned short* __restrict__ H1, unsigned short* __restrict__ H1T)
{
  __shared__ unsigned short As[4096], Bs[4096];
  __shared__ float tP1[256], tP2[256], tP3[256], tX[256];
  __shared__ float tZ1[256], tZ2[256], tZ3[256];
  __shared__ float tV1[256], tV2[256], tV3[256];
  __shared__ float tCS[128], tRS[128];

  const int t = threadIdx.x, bid = blockIdx.x;
  const int xcd = bid & 7, slot = bid >> 3;
  const int n  = xcd * 128 + (slot >> 1);
  const int nt = slot & 1;
  const int lane = t & 63, w = t >> 6, wm = w >> 1, wn = w & 1;
  const int r = lane & 15, q = lane >> 4;
  const int n0 = nt * 128;
  const float* xw = XW + (size_t)n * 1792;

  {
    int i = t;
    float xwi0 = xw[i], xwi1 = xw[256 + i], xwi2 = xw[512 + i], xwi3 = xw[768 + i];
    float xwi4 = xw[1024 + i], xwi5 = xw[1280 + i], xwu = xw[1536 + i];
    tP1[i] = SW[512 + i] - xwi2;
    tP2[i] = SW[768 + i] - xwi3;
    tP3[i] = xwu + b4[i] + bu3[i];
    tX[i]  = x[(size_t)n * HID + i];
    tZ1[i] = SW[i] - xwi0;
    tZ2[i] = SW[256 + i] - xwi1;
    tZ3[i] = xwu + b3[i] + bu3[i];
    tV1[i] = SW[1024 + i] - xwi4;
    tV2[i] = SW[1280 + i] - xwi5;
    tV3[i] = b5[i] + bu5[i];
    if (t < 128) { tCS[t] = colsum[t]; tRS[t] = rowsum[t]; }
  }
  __syncthreads();

  f32x4 acc[4][4] = {};

  for (int kb = 0; kb < 256; kb += 32) {
#pragma unroll
    for (int i = 0; i < 2; ++i) {
      int u  = i * 256 + t;
      int mi = u >> 2;
      int kc = (u & 3) * 8;
      int k  = kb + kc;
      __builtin_amdgcn_global_load_lds(GLOBAL_AS(u5b + (size_t)(n0 + mi) * 256 + k),
                                       LDS_AS(&Bs[u * 8]), 16, 0, 0);
      float cs = tCS[mi], rs = tRS[mi];
      frag a;
#pragma unroll
      for (int e = 0; e < 8; ++e) {
        int i2 = k + e;
        float pre = cs * tP1[i2] + rs * tP2[i2] + tP3[i2];
        a[e] = (short)f2bf(sigm(pre) * tX[i2]);
      }
      *(frag*)&As[u * 8] = a;
    }
    __syncthreads();

    frag af[4], bf_[4];
#pragma unroll
    for (int xx = 0; xx < 4; ++xx) {
      af[xx]  = *(const frag*)&As[(wm * 64 + xx * 16 + r) * 32 + q * 8];
      bf_[xx] = *(const frag*)&Bs[(wn * 64 + xx * 16 + r) * 32 + q * 8];
    }
#pragma unroll
    for (int xx = 0; xx < 4; ++xx)
#pragma unroll
      for (int y = 0; y < 4; ++y)
        acc[xx][y] = __builtin_amdgcn_mfma_f32_16x16x32_bf16(af[xx], bf_[y], acc[xx][y], 0, 0, 0);
    __syncthreads();
  }

#pragma unroll
  for (int xx = 0; xx < 4; ++xx) {
#pragma unroll
    for (int y = 0; y < 4; ++y) {
      int i = n0 + wn * 64 + y * 16 + r;
      frag4 pack;
#pragma unroll
      for (int g = 0; g < 4; ++g) {
        int c = wm * 64 + xx * 16 + q * 4 + g;
        float cs = tCS[c], rs = tRS[c];
        float z  = sigm(cs * tZ1[i] + rs * tZ2[i] + tZ3[i]);
        float p5 = cs * tV1[i] + rs * tV2[i] + tV3[i] + acc[xx][y][g];
        float h1 = (1.0f - z) * tX[i] + z * tanh_fast(p5);
        unsigned short hb = f2bf(h1);
        pack[g] = (short)hb;
        H1[(size_t)(n * 128 + c) * HID + i] = hb;
      }
      *(frag4*)(H1T + (size_t)n * (HID * NCLS) + (size_t)i * NCLS
                + (wm * 64 + xx * 16 + q * 4)) = pack;
    }
  }
}

// ---------------------------------------------------------------------------
// Fused layer-2 (unchanged from R2).
// ---------------------------------------------------------------------------
__global__ __launch_bounds__(256) void gemm_l2(
    const unsigned short* __restrict__ PRE, const float* __restrict__ SG,
    const unsigned short* __restrict__ H1, const unsigned short* __restrict__ u5b,
    float* __restrict__ out)
{
  __shared__ unsigned short As[4096], Bs[4096];
  const int t = threadIdx.x, bid = blockIdx.x;
  const int xcd = bid & 7, slot = bid >> 3;
  const int mt = xcd * 128 + (slot >> 1);
  const int nt = slot & 1;
  const int lane = t & 63, w = t >> 6, wm = w >> 1, wn = w & 1;
  const int r = lane & 15, q = lane >> 4;
  const int m0 = mt * 128, n0 = nt * 128;

  f32x4 acc[4][4] = {};

  for (int kb = 0; kb < 256; kb += 32) {
#pragma unroll
    for (int i = 0; i < 2; ++i) {
      int u  = i * 256 + t;
      int mi = u >> 2;
      int kc = (u & 3) * 8;
      int k  = kb + kc;
      __builtin_amdgcn_global_load_lds(GLOBAL_AS(u5b + (size_t)(n0 + mi) * 256 + k),
                                       LDS_AS(&Bs[u * 8]), 16, 0, 0);
      long row = m0 + mi;
      frag p4 = *(const frag*)(PRE + row * 768 + 256 + k);
      frag h1 = *(const frag*)(H1 + row * 256 + k);
      const float* sg = SG + (size_t)mi * 768 + 256 + k;
      frag a;
#pragma unroll
      for (int e = 0; e < 8; ++e) {
        float rv = sigm(sg[e] + bf2f((unsigned short)p4[e]));
        a[e] = (short)f2bf(rv * bf2f((unsigned short)h1[e]));
      }
      *(frag*)&As[u * 8] = a;
    }
    __syncthreads();

    frag af[4], bf_[4];
#pragma unroll
    for (int xx = 0; xx < 4; ++xx) {
      af[xx]  = *(const frag*)&As[(wm * 64 + xx * 16 + r) * 32 + q * 8];
      bf_[xx] = *(const frag*)&Bs[(wn * 64 + xx * 16 + r) * 32 + q * 8];
    }
#pragma unroll
    for (int xx = 0; xx < 4; ++xx)
#pragma unroll
      for (int y = 0; y < 4; ++y)
        acc[xx][y] = __builtin_amdgcn_mfma_f32_16x16x32_bf16(af[xx], bf_[y], acc[xx][y], 0, 0, 0);
    __syncthreads();
  }

#pragma unroll
  for (int xx = 0; xx < 4; ++xx) {
#pragma unroll
    for (int y = 0; y < 4; ++y) {
      int i = n0 + wn * 64 + y * 16 + r;
#pragma unroll
      for (int g = 0; g < 4; ++g) {
        int c = wm * 64 + xx * 16 + q * 4 + g;
        long row = m0 + c;
        float z  = sigm(SG[(size_t)c * 768 + i] + bf2f(PRE[row * 768 + i]));
        float pv = SG[(size_t)c * 768 + 512 + i] + bf2f(PRE[row * 768 + 512 + i])
                 + acc[xx][y][g];
        float h  = bf2f(H1[row * 256 + i]);
        out[row * 256 + i] = (1.0f - z) * h + z * tanh_fast(pv);
      }
    }
  }
}

// ---------------------------------------------------------------------------
// prep kernels
// ---------------------------------------------------------------------------
__global__ __launch_bounds__(256) void prep_cast(
    const float* __restrict__ x, const float* __restrict__ Kn,
    const float* __restrict__ w3, const float* __restrict__ u3,
    const float* __restrict__ w4, const float* __restrict__ w5,
    const float* __restrict__ u5,
    unsigned short* __restrict__ xb, unsigned short* __restrict__ WB,
    unsigned short* __restrict__ WB2, unsigned short* __restrict__ u5b,
    unsigned short* __restrict__ KbN, unsigned short* __restrict__ KTbN)
{
  int idx = blockIdx.x * 256 + threadIdx.x;
  if (idx < 262144) { xb[idx] = f2bf(x[idx]); return; }
  idx -= 262144;
  if (idx < 589824) {
    int col = idx / 768, j = idx % 768;
    int g = col >> 8, i = col & 255;
    float v;
    if (j < 512) { const float* wg = (g == 0) ? w3 : (g == 1) ? w4 : w5; v = wg[(size_t)i * 512 + j]; }
    else v = (g < 2) ? u3[(size_t)i * 256 + (j - 512)] : 0.0f;
    WB[(size_t)col * 768 + j] = f2bf(v);
    return;
  }
  idx -= 589824;
  if (idx < 458752) {
    int col = idx / 256, h = idx % 256;
    int b = col >> 8, i = col & 255;
    float v = (b < 6) ? ((b < 2 ? w3 : (b < 4 ? w4 : w5))[(size_t)i * 512 + (b & 1) * 256 + h])
                      : u3[(size_t)i * 256 + h];
    WB2[(size_t)col * 256 + h] = f2bf(v);
    return;
  }
  idx -= 458752;
  if (idx < 65536) { u5b[idx] = f2bf(u5[idx]); return; }
  idx -= 65536;
  if (idx < 16384) { int c = idx >> 7, k = idx & 127; KbN[idx]  = f2bf(-Kn[c * 128 + k]); return; }
  idx -= 16384;
  { int c = idx >> 7, k = idx & 127; KTbN[idx] = f2bf(-Kn[k * 128 + c]); }
}

__global__ __launch_bounds__(256) void prep_reduce(
    const float* __restrict__ x, const float* __restrict__ Kn,
    float* __restrict__ S, float* __restrict__ colsum, float* __restrict__ rowsum)
{
  int b = blockIdx.x, t = threadIdx.x;
  if (b < 8) {
    float s = 0.f;
    for (int n = 0; n < 128; ++n) s += x[(size_t)(b * 128 + n) * HID + t];
    atomicAdd(&S[t], s);
  } else if (b == 8) {
    if (t < NCLS) { float s = 0.f; for (int k = 0; k < NCLS; ++k) s += Kn[k * NCLS + t]; colsum[t] = s; }
  } else {
    if (t < NCLS) { float s = 0.f; for (int k = 0; k < NCLS; ++k) s += Kn[t * NCLS + k]; rowsum[t] = s; }
  }
}

__global__ __launch_bounds__(256) void prep_sw(
    const float* __restrict__ S, const float* __restrict__ w3,
    const float* __restrict__ w4, const float* __restrict__ w5, float* __restrict__ SW)
{
  int col = blockIdx.x * 256 + threadIdx.x;
  int b = col >> 8, i = col & 255;
  const float* w = (b < 2) ? w3 : (b < 4) ? w4 : w5;
  const float* row = w + (size_t)i * 512 + (b & 1) * 256;
  float s = 0.f;
  for (int h = 0; h < HID; ++h) s += S[h] * row[h];
  SW[col] = s;
}

// hs[c,i] += sum over 32-node chunk (grid 4096)
__global__ __launch_bounds__(256) void reduce_hs(
    const unsigned short* __restrict__ H1, float* __restrict__ hs)
{
  int bid = blockIdx.x;
  int c = bid >> 5, nch = bid & 31;
  int i = threadIdx.x;
  const unsigned short* p = H1 + (size_t)nch * 32 * NCLS * HID + (size_t)c * HID + i;
  float s = 0.f;
  for (int n = 0; n < 32; ++n) s += bf2f(p[(size_t)n * NCLS * HID]);
  atomicAdd(&hs[c * HID + i], s);
}

// hsW[k, b*256+i]  (grid 768 = 6 x 128)
__global__ __launch_bounds__(256) void p2a(
    const float* __restrict__ hs, const float* __restrict__ w3,
    const float* __restrict__ w4, const float* __restrict__ w5, float* __restrict__ hsW)
{
  __shared__ float hrow[HID];
  int k = blockIdx.x & 127, b = blockIdx.x >> 7;
  int t = threadIdx.x;
  hrow[t] = hs[k * HID + t];
  __syncthreads();
  const float* w = (b < 2) ? w3 : (b < 4) ? w4 : w5;
  const float* row = w + (size_t)t * 512 + (b & 1) * 256;
  float s = 0.f;
  for (int h = 0; h < HID; ++h) s += hrow[h] * row[h];
  hsW[(size_t)k * 1536 + b * 256 + t] = s;
}

__global__ __launch_bounds__(256) void p2b(
    const float* __restrict__ hsW, const float* __restrict__ Kn,
    const float* __restrict__ b3, const float* __restrict__ b4, const float* __restrict__ b5,
    const float* __restrict__ bu3, const float* __restrict__ bu5, float* __restrict__ SG)
{
  __shared__ float kc[NCLS], kr[NCLS];
  int c = blockIdx.x, t = threadIdx.x;
  if (t < NCLS) { kc[t] = Kn[t * NCLS + c]; kr[t] = Kn[c * NCLS + t]; }
  __syncthreads();
  for (int g = 0; g < 3; ++g) {
    int i = t;
    const float* L = hsW + (size_t)(2 * g) * 256 + i;
    const float* R = hsW + (size_t)(2 * g + 1) * 256 + i;
    float s = 0.f;
    for (int k = 0; k < NCLS; ++k) s += kc[k] * L[(size_t)k * 1536] + kr[k] * R[(size_t)k * 1536];
    const float* bg = (g == 0) ? b3 : (g == 1) ? b4 : b5;
    s += bg[i] + ((g < 2) ? bu3[i] : bu5[i]);
    SG[(size_t)c * 768 + g * 256 + i] = s;
  }
}

// ---------------------------------------------------------------------------
extern "C" void kernel_launch(void* const* d_in, const int* in_sizes, int n_in,
                              void* d_out, int out_size, void* d_ws, size_t ws_size,
                              hipStream_t stream) {
  (void)in_sizes; (void)n_in; (void)out_size; (void)ws_size;
  const float* x   = (const float*)d_in[0];
  const float* Kn  = (const float*)d_in[1];
  const float* w3  = (const float*)d_in[2];
  const float* b3  = (const float*)d_in[3];
  const float* u3  = (const float*)d_in[4];
  const float* bu3 = (const float*)d_in[5];
  const float* w4  = (const float*)d_in[6];
  const float* b4  = (const float*)d_in[7];
  const float* w5  = (const float*)d_in[8];
  const float* b5  = (const float*)d_in[9];
  const float* u5  = (const float*)d_in[10];
  const float* bu5 = (const float*)d_in[11];
  float* out = (float*)d_out;

  char* w = (char*)d_ws;
  unsigned short* PRE = (unsigned short*)(w);                 // 131072x768 bf16 (192 MiB)
  unsigned short* H1  = (unsigned short*)(w + 201326592);     // 64 MiB
  unsigned short* H1T = (unsigned short*)(w + 268435456);     // 64 MiB
  float*          XW  = (float*)(w + 335544320);              // 1024x1792 fp32
  char* misc = w + 342884352;
  float* S      = (float*)(misc);
  float* hs     = (float*)(misc + 1024);
  float* SW     = (float*)(misc + 132096);
  float* colsum = (float*)(misc + 138240);
  float* rowsum = (float*)(misc + 138752);
  float* hsW    = (float*)(misc + 139264);
  float* SG     = (float*)(misc + 925696);
  unsigned short* WB   = (unsigned short*)(misc + 1318912);
  unsigned short* WB2  = (unsigned short*)(misc + 2498560);
  unsigned short* u5b  = (unsigned short*)(misc + 3416064);
  unsigned short* KbN  = (unsigned short*)(misc + 3547136);
  unsigned short* KTbN = (unsigned short*)(misc + 3579904);
  unsigned short* xb   = (unsigned short*)(misc + 3612672);

  hipMemsetAsync(misc, 0, 132096, stream);  // S + hs

  prep_cast<<<5504, 256, 0, stream>>>(x, Kn, w3, u3, w4, w5, u5, xb, WB, WB2, u5b, KbN, KTbN);
  prep_reduce<<<10, 256, 0, stream>>>(x, Kn, S, colsum, rowsum);
  prep_sw<<<6, 256, 0, stream>>>(S, w3, w4, w5, SW);

  // XW = x @ Wcat^T  [1024,256]x[256,1792] -> fp32
  gemm_bf16<0><<<8 * 14, 256, 0, stream>>>(xb, 256, 256, xb, 256, WB2, 256, 0L,
                                           (void*)XW, 1792, 14, 256, 0xFFFFFFFFu, 8);
  // fused layer 1 -> H1, H1T
  gemm_l1<<<2048, 256, 0, stream>>>(XW, SW, x, b3, b4, b5, bu3, bu5,
                                    colsum, rowsum, u5b, H1, H1T);

  reduce_hs<<<4096, 256, 0, stream>>>(H1, hs);
  p2a<<<768, 256, 0, stream>>>(hs, w3, w4, w5, hsW);
  p2b<<<128, 256, 0, stream>>>(hsW, Kn, b3, b4, b5, bu3, bu5, SG);

  // fused per-node AVH+PRE
  gemm_node<<<1024, 512, 0, stream>>>(KTbN, KbN, H1T, H1, WB, PRE);

  // fused layer 2 -> out
  gemm_l2<<<2048, 256, 0, stream>>>(PRE, SG, H1, u5b, out);
}

// Round 4
// 829.932 us; speedup vs baseline: 1.0551x; 1.0081x over previous
//
#include <hip/hip_runtime.h>
#include <cstdint>
#include <cstddef>

// ---------------------------------------------------------------------------
// Graph_8564164788735: 2-layer class-conditioned GRU-ish propagation.
// N=1024 nodes, C=128 classes, H=256. Output fp32 [N,C,H].
//
// R4: revert R3's LDS-fused gemm_node (1 block/CU occupancy trap). Split
// AVH + PRE with specialized kernels: two-phase K loop (no per-load branch),
// __launch_bounds__(256,4) to hit 4 waves/SIMD, zero w5/u3 block skipped.
// ---------------------------------------------------------------------------

#define NODES 1024
#define NCLS  128
#define HID   256

using frag  = __attribute__((ext_vector_type(8))) short;
using frag4 = __attribute__((ext_vector_type(4))) short;
using f32x4 = __attribute__((ext_vector_type(4))) float;

__device__ __forceinline__ float bf2f(unsigned short h){
  unsigned int u = ((unsigned int)h) << 16;
  float f; __builtin_memcpy(&f, &u, 4); return f;
}
__device__ __forceinline__ unsigned short f2bf(float f){
  unsigned int u; __builtin_memcpy(&u, &f, 4);
  u = (u + 0x7fffu + ((u >> 16) & 1u)) >> 16;   // RNE
  return (unsigned short)u;
}
__device__ __forceinline__ float sigm(float x){ return 1.0f/(1.0f + __expf(-x)); }
__device__ __forceinline__ float tanh_fast(float x){ return 1.0f - 2.0f/(__expf(2.0f*x) + 1.0f); }

#define GLOBAL_AS(p) ((const __attribute__((address_space(1))) void*)(p))
#define LDS_AS(p)    ((__attribute__((address_space(3))) void*)(p))

// ---------------------------------------------------------------------------
// Generic bf16 MFMA GEMM (only used for XW). 128x128 tile, BK=32.
// ---------------------------------------------------------------------------
template<int OUT_BF16>
__global__ __launch_bounds__(256) void gemm_bf16(
    const unsigned short* __restrict__ A0, int ldA0, int K0,
    const unsigned short* __restrict__ A1, int ldA1,
    const unsigned short* __restrict__ BT, int ldB, long bStride,
    void* __restrict__ Cptr, int ldC,
    int Ntiles, int Ktot, unsigned int aMask, int Mtiles)
{
  __shared__ unsigned short As[4096];
  __shared__ unsigned short Bs[4096];
  const int t   = threadIdx.x;
  const int bid = blockIdx.x;
  const int xcd = bid & 7, slot = bid >> 3;
  const int mtPerX = (Mtiles >= 8) ? (Mtiles >> 3) : 1;
  const int mt = xcd * mtPerX + slot / Ntiles;
  const int nt = slot % Ntiles;
  const int lane = t & 63, w = t >> 6;
  const int wm = w >> 1, wn = w & 1;
  const int r = lane & 15, q = lane >> 4;
  const int m0 = mt * 128, n0 = nt * 128;
  const unsigned short* Bbase = BT + (size_t)mt * (size_t)bStride;

  f32x4 acc[4][4] = {};

  for (int kb = 0; kb < Ktot; kb += 32) {
#pragma unroll
    for (int i = 0; i < 2; ++i) {
      int u  = i * 256 + t;
      int mi = u >> 2;
      int kc = (u & 3) * 8;
      int k  = kb + kc;
      const unsigned short* ga;
      if (k < K0) ga = A0 + (size_t)((unsigned int)(m0 + mi) & aMask) * (size_t)ldA0 + k;
      else        ga = A1 + (size_t)(m0 + mi) * (size_t)ldA1 + (k - K0);
      __builtin_amdgcn_global_load_lds(GLOBAL_AS(ga), LDS_AS(&As[u * 8]), 16, 0, 0);
      const unsigned short* gb = Bbase + (size_t)(n0 + mi) * (size_t)ldB + k;
      __builtin_amdgcn_global_load_lds(GLOBAL_AS(gb), LDS_AS(&Bs[u * 8]), 16, 0, 0);
    }
    __syncthreads();

    frag af[4], bf_[4];
#pragma unroll
    for (int x = 0; x < 4; ++x) {
      af[x]  = *(const frag*)&As[(wm * 64 + x * 16 + r) * 32 + q * 8];
      bf_[x] = *(const frag*)&Bs[(wn * 64 + x * 16 + r) * 32 + q * 8];
    }
#pragma unroll
    for (int x = 0; x < 4; ++x)
#pragma unroll
      for (int y = 0; y < 4; ++y)
        acc[x][y] = __builtin_amdgcn_mfma_f32_16x16x32_bf16(af[x], bf_[y], acc[x][y], 0, 0, 0);
    __syncthreads();
  }

#pragma unroll
  for (int x = 0; x < 4; ++x) {
#pragma unroll
    for (int y = 0; y < 4; ++y) {
      int col = n0 + wn * 64 + y * 16 + r;
#pragma unroll
      for (int g = 0; g < 4; ++g) {
        long row = m0 + wm * 64 + x * 16 + q * 4 + g;
        if (OUT_BF16) ((unsigned short*)Cptr)[row * (long)ldC + col] = f2bf(acc[x][y][g]);
        else          ((float*)Cptr)[row * (long)ldC + col] = acc[x][y][g];
      }
    }
  }
}

// ---------------------------------------------------------------------------
// gemm_avh: AVH[node*128+c, colOff + nt*128 + j] = sum_k Ksrc[c,k] H1T_n[nt*128+j, k]
// A (Ksrc, 128x128) is identical for every m-tile -> L1/L2 resident.
// grid 2048 (1024 nodes x 2 nt), 256 threads, launch_bounds(256,4).
// ---------------------------------------------------------------------------
__global__ __launch_bounds__(256, 4) void gemm_avh(
    const unsigned short* __restrict__ Ksrc, const unsigned short* __restrict__ H1T,
    unsigned short* __restrict__ AVH, int colOff)
{
  __shared__ unsigned short As[4096];
  __shared__ unsigned short Bs[4096];
  const int t   = threadIdx.x;
  const int bid = blockIdx.x;
  const int xcd = bid & 7, slot = bid >> 3;
  const int node = xcd * 128 + (slot >> 1);
  const int nt = slot & 1;
  const int lane = t & 63, w = t >> 6;
  const int wm = w >> 1, wn = w & 1;
  const int r = lane & 15, q = lane >> 4;
  const int n0 = nt * 128;
  const unsigned short* Bbase = H1T + (size_t)node * (HID * NCLS);

  f32x4 acc[4][4] = {};

  for (int kb = 0; kb < 128; kb += 32) {
#pragma unroll
    for (int i = 0; i < 2; ++i) {
      int u  = i * 256 + t;
      int mi = u >> 2;
      int kc = (u & 3) * 8;
      __builtin_amdgcn_global_load_lds(GLOBAL_AS(Ksrc + (size_t)mi * 128 + kb + kc),
                                       LDS_AS(&As[u * 8]), 16, 0, 0);
      __builtin_amdgcn_global_load_lds(GLOBAL_AS(Bbase + (size_t)(n0 + mi) * 128 + kb + kc),
                                       LDS_AS(&Bs[u * 8]), 16, 0, 0);
    }
    __syncthreads();

    frag af[4], bf_[4];
#pragma unroll
    for (int x = 0; x < 4; ++x) {
      af[x]  = *(const frag*)&As[(wm * 64 + x * 16 + r) * 32 + q * 8];
      bf_[x] = *(const frag*)&Bs[(wn * 64 + x * 16 + r) * 32 + q * 8];
    }
#pragma unroll
    for (int x = 0; x < 4; ++x)
#pragma unroll
      for (int y = 0; y < 4; ++y)
        acc[x][y] = __builtin_amdgcn_mfma_f32_16x16x32_bf16(af[x], bf_[y], acc[x][y], 0, 0, 0);
    __syncthreads();
  }

#pragma unroll
  for (int x = 0; x < 4; ++x) {
#pragma unroll
    for (int y = 0; y < 4; ++y) {
      int col = colOff + n0 + wn * 64 + y * 16 + r;
#pragma unroll
      for (int g = 0; g < 4; ++g) {
        long row = (long)node * 128 + wm * 64 + x * 16 + q * 4 + g;
        AVH[row * 512 + col] = f2bf(acc[x][y][g]);
      }
    }
  }
}

// ---------------------------------------------------------------------------
// gemm_pre: PRE[:, ct*128 .. ct*128+127] for ct = ctBase..ctBase+Ntiles-1.
// Two-phase K loop: k<512 from AVH, k>=512 from H1 (u3 columns).
// Ktot=768 for gates 3,4; Ktot=512 for gate 5 (zero u3 block skipped).
// grid 1024*Ntiles, 256 threads, launch_bounds(256,4).
// ---------------------------------------------------------------------------
__global__ __launch_bounds__(256, 4) void gemm_pre(
    const unsigned short* __restrict__ AVH, const unsigned short* __restrict__ H1,
    const unsigned short* __restrict__ WB, unsigned short* __restrict__ PRE,
    int ctBase, int Ntiles, int Ktot)
{
  __shared__ unsigned short As[4096];
  __shared__ unsigned short Bs[4096];
  const int t   = threadIdx.x;
  const int bid = blockIdx.x;
  const int xcd = bid & 7, slot = bid >> 3;
  const int mt = xcd * 128 + slot / Ntiles;
  const int ct = ctBase + slot % Ntiles;
  const int lane = t & 63, w = t >> 6;
  const int wm = w >> 1, wn = w & 1;
  const int r = lane & 15, q = lane >> 4;
  const int m0 = mt * 128;
  const int mi = (2 * 256 + 0, t >> 2) ;  // placeholder to keep naming below clear
  (void)mi;

  f32x4 acc[4][4] = {};

  // phase 1: k in [0,512) from AVH
  for (int kb = 0; kb < 512; kb += 32) {
#pragma unroll
    for (int i = 0; i < 2; ++i) {
      int u  = i * 256 + t;
      int m  = u >> 2;
      int kc = (u & 3) * 8;
      __builtin_amdgcn_global_load_lds(GLOBAL_AS(AVH + (size_t)(m0 + m) * 512 + kb + kc),
                                       LDS_AS(&As[u * 8]), 16, 0, 0);
      __builtin_amdgcn_global_load_lds(GLOBAL_AS(WB + (size_t)(ct * 128 + m) * 768 + kb + kc),
                                       LDS_AS(&Bs[u * 8]), 16, 0, 0);
    }
    __syncthreads();

    frag af[4], bf_[4];
#pragma unroll
    for (int x = 0; x < 4; ++x) {
      af[x]  = *(const frag*)&As[(wm * 64 + x * 16 + r) * 32 + q * 8];
      bf_[x] = *(const frag*)&Bs[(wn * 64 + x * 16 + r) * 32 + q * 8];
    }
#pragma unroll
    for (int x = 0; x < 4; ++x)
#pragma unroll
      for (int y = 0; y < 4; ++y)
        acc[x][y] = __builtin_amdgcn_mfma_f32_16x16x32_bf16(af[x], bf_[y], acc[x][y], 0, 0, 0);
    __syncthreads();
  }

  // phase 2: k in [512,Ktot) from H1
  for (int kb = 512; kb < Ktot; kb += 32) {
#pragma unroll
    for (int i = 0; i < 2; ++i) {
      int u  = i * 256 + t;
      int m  = u >> 2;
      int kc = (u & 3) * 8;
      __builtin_amdgcn_global_load_lds(GLOBAL_AS(H1 + (size_t)(m0 + m) * 256 + (kb - 512) + kc),
                                       LDS_AS(&As[u * 8]), 16, 0, 0);
      __builtin_amdgcn_global_load_lds(GLOBAL_AS(WB + (size_t)(ct * 128 + m) * 768 + kb + kc),
                                       LDS_AS(&Bs[u * 8]), 16, 0, 0);
    }
    __syncthreads();

    frag af[4], bf_[4];
#pragma unroll
    for (int x = 0; x < 4; ++x) {
      af[x]  = *(const frag*)&As[(wm * 64 + x * 16 + r) * 32 + q * 8];
      bf_[x] = *(const frag*)&Bs[(wn * 64 + x * 16 + r) * 32 + q * 8];
    }
#pragma unroll
    for (int x = 0; x < 4; ++x)
#pragma unroll
      for (int y = 0; y < 4; ++y)
        acc[x][y] = __builtin_amdgcn_mfma_f32_16x16x32_bf16(af[x], bf_[y], acc[x][y], 0, 0, 0);
    __syncthreads();
  }

#pragma unroll
  for (int x = 0; x < 4; ++x) {
#pragma unroll
    for (int y = 0; y < 4; ++y) {
      int col = ct * 128 + wn * 64 + y * 16 + r;
#pragma unroll
      for (int g = 0; g < 4; ++g) {
        long row = m0 + wm * 64 + x * 16 + q * 4 + g;
        PRE[row * 768 + col] = f2bf(acc[x][y][g]);
      }
    }
  }
}

// ---------------------------------------------------------------------------
// Fused layer-1: T1 GEMM + GRU update; writes H1 and H1T.
// ---------------------------------------------------------------------------
__global__ __launch_bounds__(256) void gemm_l1(
    const float* __restrict__ XW, const float* __restrict__ SW,
    const float* __restrict__ x,
    const float* __restrict__ b3, const float* __restrict__ b4,
    const float* __restrict__ b5, const float* __restrict__ bu3,
    const float* __restrict__ bu5,
    const float* __restrict__ colsum, const float* __restrict__ rowsum,
    const unsigned short* __restrict__ u5b,
    unsigned short* __restrict__ H1, unsigned short* __restrict__ H1T)
{
  __shared__ unsigned short As[4096], Bs[4096];
  __shared__ float tP1[256], tP2[256], tP3[256], tX[256];
  __shared__ float tZ1[256], tZ2[256], tZ3[256];
  __shared__ float tV1[256], tV2[256], tV3[256];
  __shared__ float tCS[128], tRS[128];

  const int t = threadIdx.x, bid = blockIdx.x;
  const int xcd = bid & 7, slot = bid >> 3;
  const int n  = xcd * 128 + (slot >> 1);
  const int nt = slot & 1;
  const int lane = t & 63, w = t >> 6, wm = w >> 1, wn = w & 1;
  const int r = lane & 15, q = lane >> 4;
  const int n0 = nt * 128;
  const float* xw = XW + (size_t)n * 1792;

  {
    int i = t;
    float xwi0 = xw[i], xwi1 = xw[256 + i], xwi2 = xw[512 + i], xwi3 = xw[768 + i];
    float xwi4 = xw[1024 + i], xwi5 = xw[1280 + i], xwu = xw[1536 + i];
    tP1[i] = SW[512 + i] - xwi2;
    tP2[i] = SW[768 + i] - xwi3;
    tP3[i] = xwu + b4[i] + bu3[i];
    tX[i]  = x[(size_t)n * HID + i];
    tZ1[i] = SW[i] - xwi0;
    tZ2[i] = SW[256 + i] - xwi1;
    tZ3[i] = xwu + b3[i] + bu3[i];
    tV1[i] = SW[1024 + i] - xwi4;
    tV2[i] = SW[1280 + i] - xwi5;
    tV3[i] = b5[i] + bu5[i];
    if (t < 128) { tCS[t] = colsum[t]; tRS[t] = rowsum[t]; }
  }
  __syncthreads();

  f32x4 acc[4][4] = {};

  for (int kb = 0; kb < 256; kb += 32) {
#pragma unroll
    for (int i = 0; i < 2; ++i) {
      int u  = i * 256 + t;
      int mi = u >> 2;
      int kc = (u & 3) * 8;
      int k  = kb + kc;
      __builtin_amdgcn_global_load_lds(GLOBAL_AS(u5b + (size_t)(n0 + mi) * 256 + k),
                                       LDS_AS(&Bs[u * 8]), 16, 0, 0);
      float cs = tCS[mi], rs = tRS[mi];
      frag a;
#pragma unroll
      for (int e = 0; e < 8; ++e) {
        int i2 = k + e;
        float pre = cs * tP1[i2] + rs * tP2[i2] + tP3[i2];
        a[e] = (short)f2bf(sigm(pre) * tX[i2]);
      }
      *(frag*)&As[u * 8] = a;
    }
    __syncthreads();

    frag af[4], bf_[4];
#pragma unroll
    for (int xx = 0; xx < 4; ++xx) {
      af[xx]  = *(const frag*)&As[(wm * 64 + xx * 16 + r) * 32 + q * 8];
      bf_[xx] = *(const frag*)&Bs[(wn * 64 + xx * 16 + r) * 32 + q * 8];
    }
#pragma unroll
    for (int xx = 0; xx < 4; ++xx)
#pragma unroll
      for (int y = 0; y < 4; ++y)
        acc[xx][y] = __builtin_amdgcn_mfma_f32_16x16x32_bf16(af[xx], bf_[y], acc[xx][y], 0, 0, 0);
    __syncthreads();
  }

#pragma unroll
  for (int xx = 0; xx < 4; ++xx) {
#pragma unroll
    for (int y = 0; y < 4; ++y) {
      int i = n0 + wn * 64 + y * 16 + r;
      frag4 pack;
#pragma unroll
      for (int g = 0; g < 4; ++g) {
        int c = wm * 64 + xx * 16 + q * 4 + g;
        float cs = tCS[c], rs = tRS[c];
        float z  = sigm(cs * tZ1[i] + rs * tZ2[i] + tZ3[i]);
        float p5 = cs * tV1[i] + rs * tV2[i] + tV3[i] + acc[xx][y][g];
        float h1 = (1.0f - z) * tX[i] + z * tanh_fast(p5);
        unsigned short hb = f2bf(h1);
        pack[g] = (short)hb;
        H1[(size_t)(n * 128 + c) * HID + i] = hb;
      }
      *(frag4*)(H1T + (size_t)n * (HID * NCLS) + (size_t)i * NCLS
                + (wm * 64 + xx * 16 + q * 4)) = pack;
    }
  }
}

// ---------------------------------------------------------------------------
// Fused layer-2.
// ---------------------------------------------------------------------------
__global__ __launch_bounds__(256) void gemm_l2(
    const unsigned short* __restrict__ PRE, const float* __restrict__ SG,
    const unsigned short* __restrict__ H1, const unsigned short* __restrict__ u5b,
    float* __restrict__ out)
{
  __shared__ unsigned short As[4096], Bs[4096];
  const int t = threadIdx.x, bid = blockIdx.x;
  const int xcd = bid & 7, slot = bid >> 3;
  const int mt = xcd * 128 + (slot >> 1);
  const int nt = slot & 1;
  const int lane = t & 63, w = t >> 6, wm = w >> 1, wn = w & 1;
  const int r = lane & 15, q = lane >> 4;
  const int m0 = mt * 128, n0 = nt * 128;

  f32x4 acc[4][4] = {};

  for (int kb = 0; kb < 256; kb += 32) {
#pragma unroll
    for (int i = 0; i < 2; ++i) {
      int u  = i * 256 + t;
      int mi = u >> 2;
      int kc = (u & 3) * 8;
      int k  = kb + kc;
      __builtin_amdgcn_global_load_lds(GLOBAL_AS(u5b + (size_t)(n0 + mi) * 256 + k),
                                       LDS_AS(&Bs[u * 8]), 16, 0, 0);
      long row = m0 + mi;
      frag p4 = *(const frag*)(PRE + row * 768 + 256 + k);
      frag h1 = *(const frag*)(H1 + row * 256 + k);
      const float* sg = SG + (size_t)mi * 768 + 256 + k;
      frag a;
#pragma unroll
      for (int e = 0; e < 8; ++e) {
        float rv = sigm(sg[e] + bf2f((unsigned short)p4[e]));
        a[e] = (short)f2bf(rv * bf2f((unsigned short)h1[e]));
      }
      *(frag*)&As[u * 8] = a;
    }
    __syncthreads();

    frag af[4], bf_[4];
#pragma unroll
    for (int xx = 0; xx < 4; ++xx) {
      af[xx]  = *(const frag*)&As[(wm * 64 + xx * 16 + r) * 32 + q * 8];
      bf_[xx] = *(const frag*)&Bs[(wn * 64 + xx * 16 + r) * 32 + q * 8];
    }
#pragma unroll
    for (int xx = 0; xx < 4; ++xx)
#pragma unroll
      for (int y = 0; y < 4; ++y)
        acc[xx][y] = __builtin_amdgcn_mfma_f32_16x16x32_bf16(af[xx], bf_[y], acc[xx][y], 0, 0, 0);
    __syncthreads();
  }

#pragma unroll
  for (int xx = 0; xx < 4; ++xx) {
#pragma unroll
    for (int y = 0; y < 4; ++y) {
      int i = n0 + wn * 64 + y * 16 + r;
#pragma unroll
      for (int g = 0; g < 4; ++g) {
        int c = wm * 64 + xx * 16 + q * 4 + g;
        long row = m0 + c;
        float z  = sigm(SG[(size_t)c * 768 + i] + bf2f(PRE[row * 768 + i]));
        float pv = SG[(size_t)c * 768 + 512 + i] + bf2f(PRE[row * 768 + 512 + i])
                 + acc[xx][y][g];
        float h  = bf2f(H1[row * 256 + i]);
        out[row * 256 + i] = (1.0f - z) * h + z * tanh_fast(pv);
      }
    }
  }
}

// ---------------------------------------------------------------------------
// prep kernels
// ---------------------------------------------------------------------------
__global__ __launch_bounds__(256) void prep_cast(
    const float* __restrict__ x, const float* __restrict__ Kn,
    const float* __restrict__ w3, const float* __restrict__ u3,
    const float* __restrict__ w4, const float* __restrict__ w5,
    const float* __restrict__ u5,
    unsigned short* __restrict__ xb, unsigned short* __restrict__ WB,
    unsigned short* __restrict__ WB2, unsigned short* __restrict__ u5b,
    unsigned short* __restrict__ KbN, unsigned short* __restrict__ KTbN)
{
  int idx = blockIdx.x * 256 + threadIdx.x;
  if (idx < 262144) { xb[idx] = f2bf(x[idx]); return; }
  idx -= 262144;
  if (idx < 589824) {
    int col = idx / 768, j = idx % 768;
    int g = col >> 8, i = col & 255;
    float v;
    if (j < 512) { const float* wg = (g == 0) ? w3 : (g == 1) ? w4 : w5; v = wg[(size_t)i * 512 + j]; }
    else v = (g < 2) ? u3[(size_t)i * 256 + (j - 512)] : 0.0f;
    WB[(size_t)col * 768 + j] = f2bf(v);
    return;
  }
  idx -= 589824;
  if (idx < 458752) {
    int col = idx / 256, h = idx % 256;
    int b = col >> 8, i = col & 255;
    float v = (b < 6) ? ((b < 2 ? w3 : (b < 4 ? w4 : w5))[(size_t)i * 512 + (b & 1) * 256 + h])
                      : u3[(size_t)i * 256 + h];
    WB2[(size_t)col * 256 + h] = f2bf(v);
    return;
  }
  idx -= 458752;
  if (idx < 65536) { u5b[idx] = f2bf(u5[idx]); return; }
  idx -= 65536;
  if (idx < 16384) { int c = idx >> 7, k = idx & 127; KbN[idx]  = f2bf(-Kn[c * 128 + k]); return; }
  idx -= 16384;
  { int c = idx >> 7, k = idx & 127; KTbN[idx] = f2bf(-Kn[k * 128 + c]); }
}

__global__ __launch_bounds__(256) void prep_reduce(
    const float* __restrict__ x, const float* __restrict__ Kn,
    float* __restrict__ S, float* __restrict__ colsum, float* __restrict__ rowsum)
{
  int b = blockIdx.x, t = threadIdx.x;
  if (b < 8) {
    float s = 0.f;
    for (int n = 0; n < 128; ++n) s += x[(size_t)(b * 128 + n) * HID + t];
    atomicAdd(&S[t], s);
  } else if (b == 8) {
    if (t < NCLS) { float s = 0.f; for (int k = 0; k < NCLS; ++k) s += Kn[k * NCLS + t]; colsum[t] = s; }
  } else {
    if (t < NCLS) { float s = 0.f; for (int k = 0; k < NCLS; ++k) s += Kn[t * NCLS + k]; rowsum[t] = s; }
  }
}

__global__ __launch_bounds__(256) void prep_sw(
    const float* __restrict__ S, const float* __restrict__ w3,
    const float* __restrict__ w4, const float* __restrict__ w5, float* __restrict__ SW)
{
  int col = blockIdx.x * 256 + threadIdx.x;
  int b = col >> 8, i = col & 255;
  const float* w = (b < 2) ? w3 : (b < 4) ? w4 : w5;
  const float* row = w + (size_t)i * 512 + (b & 1) * 256;
  float s = 0.f;
  for (int h = 0; h < HID; ++h) s += S[h] * row[h];
  SW[col] = s;
}

__global__ __launch_bounds__(256) void reduce_hs(
    const unsigned short* __restrict__ H1, float* __restrict__ hs)
{
  int bid = blockIdx.x;
  int c = bid >> 5, nch = bid & 31;
  int i = threadIdx.x;
  const unsigned short* p = H1 + (size_t)nch * 32 * NCLS * HID + (size_t)c * HID + i;
  float s = 0.f;
  for (int n = 0; n < 32; ++n) s += bf2f(p[(size_t)n * NCLS * HID]);
  atomicAdd(&hs[c * HID + i], s);
}

__global__ __launch_bounds__(256) void p2a(
    const float* __restrict__ hs, const float* __restrict__ w3,
    const float* __restrict__ w4, const float* __restrict__ w5, float* __restrict__ hsW)
{
  __shared__ float hrow[HID];
  int k = blockIdx.x & 127, b = blockIdx.x >> 7;
  int t = threadIdx.x;
  hrow[t] = hs[k * HID + t];
  __syncthreads();
  const float* w = (b < 2) ? w3 : (b < 4) ? w4 : w5;
  const float* row = w + (size_t)t * 512 + (b & 1) * 256;
  float s = 0.f;
  for (int h = 0; h < HID; ++h) s += hrow[h] * row[h];
  hsW[(size_t)k * 1536 + b * 256 + t] = s;
}

__global__ __launch_bounds__(256) void p2b(
    const float* __restrict__ hsW, const float* __restrict__ Kn,
    const float* __restrict__ b3, const float* __restrict__ b4, const float* __restrict__ b5,
    const float* __restrict__ bu3, const float* __restrict__ bu5, float* __restrict__ SG)
{
  __shared__ float kc[NCLS], kr[NCLS];
  int c = blockIdx.x, t = threadIdx.x;
  if (t < NCLS) { kc[t] = Kn[t * NCLS + c]; kr[t] = Kn[c * NCLS + t]; }
  __syncthreads();
  for (int g = 0; g < 3; ++g) {
    int i = t;
    const float* L = hsW + (size_t)(2 * g) * 256 + i;
    const float* R = hsW + (size_t)(2 * g + 1) * 256 + i;
    float s = 0.f;
    for (int k = 0; k < NCLS; ++k) s += kc[k] * L[(size_t)k * 1536] + kr[k] * R[(size_t)k * 1536];
    const float* bg = (g == 0) ? b3 : (g == 1) ? b4 : b5;
    s += bg[i] + ((g < 2) ? bu3[i] : bu5[i]);
    SG[(size_t)c * 768 + g * 256 + i] = s;
  }
}

// ---------------------------------------------------------------------------
extern "C" void kernel_launch(void* const* d_in, const int* in_sizes, int n_in,
                              void* d_out, int out_size, void* d_ws, size_t ws_size,
                              hipStream_t stream) {
  (void)in_sizes; (void)n_in; (void)out_size; (void)ws_size;
  const float* x   = (const float*)d_in[0];
  const float* Kn  = (const float*)d_in[1];
  const float* w3  = (const float*)d_in[2];
  const float* b3  = (const float*)d_in[3];
  const float* u3  = (const float*)d_in[4];
  const float* bu3 = (const float*)d_in[5];
  const float* w4  = (const float*)d_in[6];
  const float* b4  = (const float*)d_in[7];
  const float* w5  = (const float*)d_in[8];
  const float* b5  = (const float*)d_in[9];
  const float* u5  = (const float*)d_in[10];
  const float* bu5 = (const float*)d_in[11];
  float* out = (float*)d_out;

  char* w = (char*)d_ws;
  unsigned short* AVH = (unsigned short*)(w);                 // 131072x512 bf16 (128 MiB)
  unsigned short* PRE = (unsigned short*)(w + 134217728);     // 131072x768 bf16 (192 MiB)
  unsigned short* H1  = (unsigned short*)(w + 335544320);     // 64 MiB
  unsigned short* H1T = (unsigned short*)(w + 402653184);     // 64 MiB
  float*          XW  = (float*)(w + 469762048);              // 1024x1792 fp32
  char* misc = w + 477102080;
  float* S      = (float*)(misc);
  float* hs     = (float*)(misc + 1024);
  float* SW     = (float*)(misc + 132096);
  float* colsum = (float*)(misc + 138240);
  float* rowsum = (float*)(misc + 138752);
  float* hsW    = (float*)(misc + 139264);
  float* SG     = (float*)(misc + 925696);
  unsigned short* WB   = (unsigned short*)(misc + 1318912);
  unsigned short* WB2  = (unsigned short*)(misc + 2498560);
  unsigned short* u5b  = (unsigned short*)(misc + 3416064);
  unsigned short* KbN  = (unsigned short*)(misc + 3547136);
  unsigned short* KTbN = (unsigned short*)(misc + 3579904);
  unsigned short* xb   = (unsigned short*)(misc + 3612672);

  hipMemsetAsync(misc, 0, 132096, stream);  // S + hs

  prep_cast<<<5504, 256, 0, stream>>>(x, Kn, w3, u3, w4, w5, u5, xb, WB, WB2, u5b, KbN, KTbN);
  prep_reduce<<<10, 256, 0, stream>>>(x, Kn, S, colsum, rowsum);
  prep_sw<<<6, 256, 0, stream>>>(S, w3, w4, w5, SW);

  // XW = x @ Wcat^T  [1024,256]x[256,1792] -> fp32
  gemm_bf16<0><<<8 * 14, 256, 0, stream>>>(xb, 256, 256, xb, 256, WB2, 256, 0L,
                                           (void*)XW, 1792, 14, 256, 0xFFFFFFFFu, 8);
  // fused layer 1 -> H1, H1T
  gemm_l1<<<2048, 256, 0, stream>>>(XW, SW, x, b3, b4, b5, bu3, bu5,
                                    colsum, rowsum, u5b, H1, H1T);

  reduce_hs<<<4096, 256, 0, stream>>>(H1, hs);
  p2a<<<768, 256, 0, stream>>>(hs, w3, w4, w5, hsW);
  p2b<<<128, 256, 0, stream>>>(hsW, Kn, b3, b4, b5, bu3, bu5, SG);

  // AVH[:,0:256] = -K^T H ; AVH[:,256:512] = -K H
  gemm_avh<<<2048, 256, 0, stream>>>(KTbN, H1T, AVH, 0);
  gemm_avh<<<2048, 256, 0, stream>>>(KbN, H1T, AVH, 256);

  // PRE: gates 3,4 (K=768 incl. u3), gate 5 (K=512, zero block skipped)
  gemm_pre<<<1024 * 4, 256, 0, stream>>>(AVH, H1, WB, PRE, 0, 4, 768);
  gemm_pre<<<1024 * 2, 256, 0, stream>>>(AVH, H1, WB, PRE, 4, 2, 512);

  // fused layer 2 -> out
  gemm_l2<<<2048, 256, 0, stream>>>(PRE, SG, H1, u5b, out);
}

// Round 5
// 776.454 us; speedup vs baseline: 1.1278x; 1.0689x over previous
//
#include <hip/hip_runtime.h>
#include <cstdint>
#include <cstddef>

// ---------------------------------------------------------------------------
// Graph_8564164788735: 2-layer class-conditioned GRU-ish propagation.
// N=1024 nodes, C=128 classes, H=256. Output fp32 [N,C,H].
//
// R5: merged gemm_pre with BK=64 + XOR-8 chunk swizzle (conflict-free frag
// reads, half the barrier drains); AVH mini-GEMMs fused into gemm_l1's
// epilogue (H1T buffer + both gemm_avh launches deleted); XOR-4 swizzle in
// gemm_l1/l2 main loops.
// ---------------------------------------------------------------------------

#define NODES 1024
#define NCLS  128
#define HID   256

using frag  = __attribute__((ext_vector_type(8))) short;
using frag4 = __attribute__((ext_vector_type(4))) short;
using f32x4 = __attribute__((ext_vector_type(4))) float;

__device__ __forceinline__ float bf2f(unsigned short h){
  unsigned int u = ((unsigned int)h) << 16;
  float f; __builtin_memcpy(&f, &u, 4); return f;
}
__device__ __forceinline__ unsigned short f2bf(float f){
  unsigned int u; __builtin_memcpy(&u, &f, 4);
  u = (u + 0x7fffu + ((u >> 16) & 1u)) >> 16;   // RNE
  return (unsigned short)u;
}
__device__ __forceinline__ float sigm(float x){ return 1.0f/(1.0f + __expf(-x)); }
__device__ __forceinline__ float tanh_fast(float x){ return 1.0f - 2.0f/(__expf(2.0f*x) + 1.0f); }

#define GLOBAL_AS(p) ((const __attribute__((address_space(1))) void*)(p))
#define LDS_AS(p)    ((__attribute__((address_space(3))) void*)(p))

// ---------------------------------------------------------------------------
// Generic bf16 MFMA GEMM (only used for XW). 128x128 tile, BK=32.
// ---------------------------------------------------------------------------
template<int OUT_BF16>
__global__ __launch_bounds__(256) void gemm_bf16(
    const unsigned short* __restrict__ A0, int ldA0, int K0,
    const unsigned short* __restrict__ A1, int ldA1,
    const unsigned short* __restrict__ BT, int ldB, long bStride,
    void* __restrict__ Cptr, int ldC,
    int Ntiles, int Ktot, unsigned int aMask, int Mtiles)
{
  __shared__ unsigned short As[4096];
  __shared__ unsigned short Bs[4096];
  const int t   = threadIdx.x;
  const int bid = blockIdx.x;
  const int xcd = bid & 7, slot = bid >> 3;
  const int mtPerX = (Mtiles >= 8) ? (Mtiles >> 3) : 1;
  const int mt = xcd * mtPerX + slot / Ntiles;
  const int nt = slot % Ntiles;
  const int lane = t & 63, w = t >> 6;
  const int wm = w >> 1, wn = w & 1;
  const int r = lane & 15, q = lane >> 4;
  const int m0 = mt * 128, n0 = nt * 128;
  const unsigned short* Bbase = BT + (size_t)mt * (size_t)bStride;

  f32x4 acc[4][4] = {};

  for (int kb = 0; kb < Ktot; kb += 32) {
#pragma unroll
    for (int i = 0; i < 2; ++i) {
      int u  = i * 256 + t;
      int mi = u >> 2;
      int kc = (u & 3) * 8;
      int k  = kb + kc;
      const unsigned short* ga;
      if (k < K0) ga = A0 + (size_t)((unsigned int)(m0 + mi) & aMask) * (size_t)ldA0 + k;
      else        ga = A1 + (size_t)(m0 + mi) * (size_t)ldA1 + (k - K0);
      __builtin_amdgcn_global_load_lds(GLOBAL_AS(ga), LDS_AS(&As[u * 8]), 16, 0, 0);
      const unsigned short* gb = Bbase + (size_t)(n0 + mi) * (size_t)ldB + k;
      __builtin_amdgcn_global_load_lds(GLOBAL_AS(gb), LDS_AS(&Bs[u * 8]), 16, 0, 0);
    }
    __syncthreads();

    frag af[4], bf_[4];
#pragma unroll
    for (int x = 0; x < 4; ++x) {
      af[x]  = *(const frag*)&As[(wm * 64 + x * 16 + r) * 32 + q * 8];
      bf_[x] = *(const frag*)&Bs[(wn * 64 + x * 16 + r) * 32 + q * 8];
    }
#pragma unroll
    for (int x = 0; x < 4; ++x)
#pragma unroll
      for (int y = 0; y < 4; ++y)
        acc[x][y] = __builtin_amdgcn_mfma_f32_16x16x32_bf16(af[x], bf_[y], acc[x][y], 0, 0, 0);
    __syncthreads();
  }

#pragma unroll
  for (int x = 0; x < 4; ++x) {
#pragma unroll
    for (int y = 0; y < 4; ++y) {
      int col = n0 + wn * 64 + y * 16 + r;
#pragma unroll
      for (int g = 0; g < 4; ++g) {
        long row = m0 + wm * 64 + x * 16 + q * 4 + g;
        if (OUT_BF16) ((unsigned short*)Cptr)[row * (long)ldC + col] = f2bf(acc[x][y][g]);
        else          ((float*)Cptr)[row * (long)ldC + col] = acc[x][y][g];
      }
    }
  }
}

// ---------------------------------------------------------------------------
// gemm_pre (merged, BK=64, XOR-8 swizzle):
// PRE[:, ct*128..+127], ct=0..5. Phase1 k<512 from AVH; phase2 (ct<4 only)
// k in [512,768) from H1 (u3 cols). grid 6144 = 8 xcd x 128 mt x 6 ct.
// LDS physical chunk c of row mi holds logical k-chunk c^(mi&7); frag read
// for logical chunk (kh*4+q) uses physical ((kh*4+q)^(row&7)) -> ~2-way.
// ---------------------------------------------------------------------------
__global__ __launch_bounds__(256, 4) void gemm_pre(
    const unsigned short* __restrict__ AVH, const unsigned short* __restrict__ H1,
    const unsigned short* __restrict__ WB, unsigned short* __restrict__ PRE)
{
  __shared__ unsigned short As[8192];   // 128 x 64
  __shared__ unsigned short Bs[8192];
  const int t   = threadIdx.x;
  const int bid = blockIdx.x;
  const int xcd = bid & 7, slot = bid >> 3;
  const int mt = xcd * 128 + slot / 6;
  const int ct = slot % 6;
  const int lane = t & 63, w = t >> 6;
  const int wm = w >> 1, wn = w & 1;
  const int r = lane & 15, q = lane >> 4;
  const int m0 = mt * 128;
  const unsigned short* Wrow = WB + (size_t)(ct * 128) * 768;

  f32x4 acc[4][4] = {};

  // phase 1: k in [0,512) from AVH
  for (int kb = 0; kb < 512; kb += 64) {
#pragma unroll
    for (int i = 0; i < 4; ++i) {
      int u  = i * 256 + t;
      int mi = u >> 3;
      int gc = (u & 7) ^ (mi & 7);
      __builtin_amdgcn_global_load_lds(GLOBAL_AS(AVH + (size_t)(m0 + mi) * 512 + kb + gc * 8),
                                       LDS_AS(&As[u * 8]), 16, 0, 0);
      __builtin_amdgcn_global_load_lds(GLOBAL_AS(Wrow + (size_t)mi * 768 + kb + gc * 8),
                                       LDS_AS(&Bs[u * 8]), 16, 0, 0);
    }
    __syncthreads();
#pragma unroll
    for (int kh = 0; kh < 2; ++kh) {
      frag af[4], bf_[4];
#pragma unroll
      for (int x = 0; x < 4; ++x) {
        int ra = wm * 64 + x * 16 + r;
        int rb = wn * 64 + x * 16 + r;
        af[x]  = *(const frag*)&As[ra * 64 + (((kh * 4 + q) ^ (ra & 7)) * 8)];
        bf_[x] = *(const frag*)&Bs[rb * 64 + (((kh * 4 + q) ^ (rb & 7)) * 8)];
      }
#pragma unroll
      for (int x = 0; x < 4; ++x)
#pragma unroll
        for (int y = 0; y < 4; ++y)
          acc[x][y] = __builtin_amdgcn_mfma_f32_16x16x32_bf16(af[x], bf_[y], acc[x][y], 0, 0, 0);
    }
    __syncthreads();
  }

  // phase 2: k in [512,768) from H1 (gates 3,4 only)
  if (ct < 4) {
    for (int kb = 0; kb < 256; kb += 64) {
#pragma unroll
      for (int i = 0; i < 4; ++i) {
        int u  = i * 256 + t;
        int mi = u >> 3;
        int gc = (u & 7) ^ (mi & 7);
        __builtin_amdgcn_global_load_lds(GLOBAL_AS(H1 + (size_t)(m0 + mi) * 256 + kb + gc * 8),
                                         LDS_AS(&As[u * 8]), 16, 0, 0);
        __builtin_amdgcn_global_load_lds(GLOBAL_AS(Wrow + (size_t)mi * 768 + 512 + kb + gc * 8),
                                         LDS_AS(&Bs[u * 8]), 16, 0, 0);
      }
      __syncthreads();
#pragma unroll
      for (int kh = 0; kh < 2; ++kh) {
        frag af[4], bf_[4];
#pragma unroll
        for (int x = 0; x < 4; ++x) {
          int ra = wm * 64 + x * 16 + r;
          int rb = wn * 64 + x * 16 + r;
          af[x]  = *(const frag*)&As[ra * 64 + (((kh * 4 + q) ^ (ra & 7)) * 8)];
          bf_[x] = *(const frag*)&Bs[rb * 64 + (((kh * 4 + q) ^ (rb & 7)) * 8)];
        }
#pragma unroll
        for (int x = 0; x < 4; ++x)
#pragma unroll
          for (int y = 0; y < 4; ++y)
            acc[x][y] = __builtin_amdgcn_mfma_f32_16x16x32_bf16(af[x], bf_[y], acc[x][y], 0, 0, 0);
      }
      __syncthreads();
    }
  }

#pragma unroll
  for (int x = 0; x < 4; ++x) {
#pragma unroll
    for (int y = 0; y < 4; ++y) {
      int col = ct * 128 + wn * 64 + y * 16 + r;
#pragma unroll
      for (int g = 0; g < 4; ++g) {
        long row = m0 + wm * 64 + x * 16 + q * 4 + g;
        PRE[row * 768 + col] = f2bf(acc[x][y][g]);
      }
    }
  }
}

// ---------------------------------------------------------------------------
// Fused layer-1: T1 GEMM + GRU update; epilogue writes H1 and (via LDS h1^T)
// runs two K=128 mini-GEMMs against -K^T / -K to produce this node's AVH
// columns directly. One block = (node, hidden half). grid 2048.
// ---------------------------------------------------------------------------
__global__ __launch_bounds__(256) void gemm_l1(
    const float* __restrict__ XW, const float* __restrict__ SW,
    const float* __restrict__ x,
    const float* __restrict__ b3, const float* __restrict__ b4,
    const float* __restrict__ b5, const float* __restrict__ bu3,
    const float* __restrict__ bu5,
    const float* __restrict__ colsum, const float* __restrict__ rowsum,
    const unsigned short* __restrict__ u5b,
    const unsigned short* __restrict__ KTbN, const unsigned short* __restrict__ KbN,
    unsigned short* __restrict__ H1, unsigned short* __restrict__ AVH)
{
  __shared__ unsigned short SM[17408];   // As[0:4096] | Bs[4096:8192]; L = SM (epi)
  unsigned short* As = SM;
  unsigned short* Bs = SM + 4096;
  unsigned short* L  = SM;               // [128 j][136] : L[j][c] = h1[c][j]
  __shared__ float tP1[256], tP2[256], tP3[256], tX[256];
  __shared__ float tZ1[256], tZ2[256], tZ3[256];
  __shared__ float tV1[256], tV2[256], tV3[256];
  __shared__ float tCS[128], tRS[128];

  const int t = threadIdx.x, bid = blockIdx.x;
  const int xcd = bid & 7, slot = bid >> 3;
  const int n  = xcd * 128 + (slot >> 1);
  const int nt = slot & 1;
  const int lane = t & 63, w = t >> 6, wm = w >> 1, wn = w & 1;
  const int r = lane & 15, q = lane >> 4;
  const int n0 = nt * 128;
  const float* xw = XW + (size_t)n * 1792;

  {
    int i = t;
    float xwi0 = xw[i], xwi1 = xw[256 + i], xwi2 = xw[512 + i], xwi3 = xw[768 + i];
    float xwi4 = xw[1024 + i], xwi5 = xw[1280 + i], xwu = xw[1536 + i];
    tP1[i] = SW[512 + i] - xwi2;
    tP2[i] = SW[768 + i] - xwi3;
    tP3[i] = xwu + b4[i] + bu3[i];
    tX[i]  = x[(size_t)n * HID + i];
    tZ1[i] = SW[i] - xwi0;
    tZ2[i] = SW[256 + i] - xwi1;
    tZ3[i] = xwu + b3[i] + bu3[i];
    tV1[i] = SW[1024 + i] - xwi4;
    tV2[i] = SW[1280 + i] - xwi5;
    tV3[i] = b5[i] + bu5[i];
    if (t < 128) { tCS[t] = colsum[t]; tRS[t] = rowsum[t]; }
  }
  __syncthreads();

  f32x4 acc[4][4] = {};

  for (int kb = 0; kb < 256; kb += 32) {
#pragma unroll
    for (int i = 0; i < 2; ++i) {
      int u  = i * 256 + t;
      int mi = u >> 2;
      int c  = u & 3;
      int kc = c * 8;
      int k  = kb + kc;
      int gc = c ^ (mi & 3);
      __builtin_amdgcn_global_load_lds(GLOBAL_AS(u5b + (size_t)(n0 + mi) * 256 + kb + gc * 8),
                                       LDS_AS(&Bs[u * 8]), 16, 0, 0);
      float cs = tCS[mi], rs = tRS[mi];
      frag a;
#pragma unroll
      for (int e = 0; e < 8; ++e) {
        int i2 = k + e;
        float pre = cs * tP1[i2] + rs * tP2[i2] + tP3[i2];
        a[e] = (short)f2bf(sigm(pre) * tX[i2]);
      }
      *(frag*)&As[mi * 32 + (c ^ (mi & 3)) * 8] = a;
    }
    __syncthreads();

    frag af[4], bf_[4];
#pragma unroll
    for (int xx = 0; xx < 4; ++xx) {
      int ra = wm * 64 + xx * 16 + r;
      int rb = wn * 64 + xx * 16 + r;
      af[xx]  = *(const frag*)&As[ra * 32 + ((q ^ (ra & 3)) * 8)];
      bf_[xx] = *(const frag*)&Bs[rb * 32 + ((q ^ (rb & 3)) * 8)];
    }
#pragma unroll
    for (int xx = 0; xx < 4; ++xx)
#pragma unroll
      for (int y = 0; y < 4; ++y)
        acc[xx][y] = __builtin_amdgcn_mfma_f32_16x16x32_bf16(af[xx], bf_[y], acc[xx][y], 0, 0, 0);
    __syncthreads();
  }

  // epilogue 1: GRU update -> H1 (global) and L[j][c]=h1[c][j] (LDS)
#pragma unroll
  for (int xx = 0; xx < 4; ++xx) {
#pragma unroll
    for (int y = 0; y < 4; ++y) {
      int j = wn * 64 + y * 16 + r;        // local hidden col
      int i = n0 + j;                      // global hidden col
      frag4 pack;
#pragma unroll
      for (int g = 0; g < 4; ++g) {
        int c = wm * 64 + xx * 16 + q * 4 + g;
        float cs = tCS[c], rs = tRS[c];
        float z  = sigm(cs * tZ1[i] + rs * tZ2[i] + tZ3[i]);
        float p5 = cs * tV1[i] + rs * tV2[i] + tV3[i] + acc[xx][y][g];
        float h1 = (1.0f - z) * tX[i] + z * tanh_fast(p5);
        unsigned short hb = f2bf(h1);
        pack[g] = (short)hb;
        H1[(size_t)(n * 128 + c) * HID + i] = hb;
      }
      *(frag4*)&L[j * 136 + (wm * 64 + xx * 16 + q * 4)] = pack;
    }
  }
  __syncthreads();

  // epilogue 2: AVH_n[:, s*256 + n0 + j] = sum_c Ksrc[c',c] * h1[c][j]
#pragma unroll
  for (int s = 0; s < 2; ++s) {
    const unsigned short* Ks = s ? KbN : KTbN;
    f32x4 a2[4][4] = {};
#pragma unroll
    for (int kb = 0; kb < 4; ++kb) {
      frag af[4], bf_[4];
#pragma unroll
      for (int xx = 0; xx < 4; ++xx) {
        int cp = wm * 64 + xx * 16 + r;
        af[xx] = *(const frag*)(Ks + (size_t)cp * 128 + kb * 32 + q * 8);
        int j = wn * 64 + xx * 16 + r;
        bf_[xx] = *(const frag*)&L[j * 136 + kb * 32 + q * 8];
      }
#pragma unroll
      for (int xx = 0; xx < 4; ++xx)
#pragma unroll
        for (int y = 0; y < 4; ++y)
          a2[xx][y] = __builtin_amdgcn_mfma_f32_16x16x32_bf16(af[xx], bf_[y], a2[xx][y], 0, 0, 0);
    }
#pragma unroll
    for (int xx = 0; xx < 4; ++xx)
#pragma unroll
      for (int y = 0; y < 4; ++y) {
        int col = s * 256 + n0 + wn * 64 + y * 16 + r;
#pragma unroll
        for (int g = 0; g < 4; ++g) {
          int cp = wm * 64 + xx * 16 + q * 4 + g;
          AVH[(size_t)(n * 128 + cp) * 512 + col] = f2bf(a2[xx][y][g]);
        }
      }
  }
}

// ---------------------------------------------------------------------------
// Fused layer-2 (XOR-4 swizzled As/Bs).
// ---------------------------------------------------------------------------
__global__ __launch_bounds__(256) void gemm_l2(
    const unsigned short* __restrict__ PRE, const float* __restrict__ SG,
    const unsigned short* __restrict__ H1, const unsigned short* __restrict__ u5b,
    float* __restrict__ out)
{
  __shared__ unsigned short As[4096], Bs[4096];
  const int t = threadIdx.x, bid = blockIdx.x;
  const int xcd = bid & 7, slot = bid >> 3;
  const int mt = xcd * 128 + (slot >> 1);
  const int nt = slot & 1;
  const int lane = t & 63, w = t >> 6, wm = w >> 1, wn = w & 1;
  const int r = lane & 15, q = lane >> 4;
  const int m0 = mt * 128, n0 = nt * 128;

  f32x4 acc[4][4] = {};

  for (int kb = 0; kb < 256; kb += 32) {
#pragma unroll
    for (int i = 0; i < 2; ++i) {
      int u  = i * 256 + t;
      int mi = u >> 2;
      int c  = u & 3;
      int k  = kb + c * 8;
      int gc = c ^ (mi & 3);
      __builtin_amdgcn_global_load_lds(GLOBAL_AS(u5b + (size_t)(n0 + mi) * 256 + kb + gc * 8),
                                       LDS_AS(&Bs[u * 8]), 16, 0, 0);
      long row = m0 + mi;
      frag p4 = *(const frag*)(PRE + row * 768 + 256 + k);
      frag h1 = *(const frag*)(H1 + row * 256 + k);
      const float* sg = SG + (size_t)mi * 768 + 256 + k;
      frag a;
#pragma unroll
      for (int e = 0; e < 8; ++e) {
        float rv = sigm(sg[e] + bf2f((unsigned short)p4[e]));
        a[e] = (short)f2bf(rv * bf2f((unsigned short)h1[e]));
      }
      *(frag*)&As[mi * 32 + (c ^ (mi & 3)) * 8] = a;
    }
    __syncthreads();

    frag af[4], bf_[4];
#pragma unroll
    for (int xx = 0; xx < 4; ++xx) {
      int ra = wm * 64 + xx * 16 + r;
      int rb = wn * 64 + xx * 16 + r;
      af[xx]  = *(const frag*)&As[ra * 32 + ((q ^ (ra & 3)) * 8)];
      bf_[xx] = *(const frag*)&Bs[rb * 32 + ((q ^ (rb & 3)) * 8)];
    }
#pragma unroll
    for (int xx = 0; xx < 4; ++xx)
#pragma unroll
      for (int y = 0; y < 4; ++y)
        acc[xx][y] = __builtin_amdgcn_mfma_f32_16x16x32_bf16(af[xx], bf_[y], acc[xx][y], 0, 0, 0);
    __syncthreads();
  }

#pragma unroll
  for (int xx = 0; xx < 4; ++xx) {
#pragma unroll
    for (int y = 0; y < 4; ++y) {
      int i = n0 + wn * 64 + y * 16 + r;
#pragma unroll
      for (int g = 0; g < 4; ++g) {
        int c = wm * 64 + xx * 16 + q * 4 + g;
        long row = m0 + c;
        float z  = sigm(SG[(size_t)c * 768 + i] + bf2f(PRE[row * 768 + i]));
        float pv = SG[(size_t)c * 768 + 512 + i] + bf2f(PRE[row * 768 + 512 + i])
                 + acc[xx][y][g];
        float h  = bf2f(H1[row * 256 + i]);
        out[row * 256 + i] = (1.0f - z) * h + z * tanh_fast(pv);
      }
    }
  }
}

// ---------------------------------------------------------------------------
// prep kernels
// ---------------------------------------------------------------------------
__global__ __launch_bounds__(256) void prep_cast(
    const float* __restrict__ x, const float* __restrict__ Kn,
    const float* __restrict__ w3, const float* __restrict__ u3,
    const float* __restrict__ w4, const float* __restrict__ w5,
    const float* __restrict__ u5,
    unsigned short* __restrict__ xb, unsigned short* __restrict__ WB,
    unsigned short* __restrict__ WB2, unsigned short* __restrict__ u5b,
    unsigned short* __restrict__ KbN, unsigned short* __restrict__ KTbN)
{
  int idx = blockIdx.x * 256 + threadIdx.x;
  if (idx < 262144) { xb[idx] = f2bf(x[idx]); return; }
  idx -= 262144;
  if (idx < 589824) {
    int col = idx / 768, j = idx % 768;
    int g = col >> 8, i = col & 255;
    float v;
    if (j < 512) { const float* wg = (g == 0) ? w3 : (g == 1) ? w4 : w5; v = wg[(size_t)i * 512 + j]; }
    else v = (g < 2) ? u3[(size_t)i * 256 + (j - 512)] : 0.0f;
    WB[(size_t)col * 768 + j] = f2bf(v);
    return;
  }
  idx -= 589824;
  if (idx < 458752) {
    int col = idx / 256, h = idx % 256;
    int b = col >> 8, i = col & 255;
    float v = (b < 6) ? ((b < 2 ? w3 : (b < 4 ? w4 : w5))[(size_t)i * 512 + (b & 1) * 256 + h])
                      : u3[(size_t)i * 256 + h];
    WB2[(size_t)col * 256 + h] = f2bf(v);
    return;
  }
  idx -= 458752;
  if (idx < 65536) { u5b[idx] = f2bf(u5[idx]); return; }
  idx -= 65536;
  if (idx < 16384) { int c = idx >> 7, k = idx & 127; KbN[idx]  = f2bf(-Kn[c * 128 + k]); return; }
  idx -= 16384;
  { int c = idx >> 7, k = idx & 127; KTbN[idx] = f2bf(-Kn[k * 128 + c]); }
}

__global__ __launch_bounds__(256) void prep_reduce(
    const float* __restrict__ x, const float* __restrict__ Kn,
    float* __restrict__ S, float* __restrict__ colsum, float* __restrict__ rowsum)
{
  int b = blockIdx.x, t = threadIdx.x;
  if (b < 8) {
    float s = 0.f;
    for (int n = 0; n < 128; ++n) s += x[(size_t)(b * 128 + n) * HID + t];
    atomicAdd(&S[t], s);
  } else if (b == 8) {
    if (t < NCLS) { float s = 0.f; for (int k = 0; k < NCLS; ++k) s += Kn[k * NCLS + t]; colsum[t] = s; }
  } else {
    if (t < NCLS) { float s = 0.f; for (int k = 0; k < NCLS; ++k) s += Kn[t * NCLS + k]; rowsum[t] = s; }
  }
}

__global__ __launch_bounds__(256) void prep_sw(
    const float* __restrict__ S, const float* __restrict__ w3,
    const float* __restrict__ w4, const float* __restrict__ w5, float* __restrict__ SW)
{
  int col = blockIdx.x * 256 + threadIdx.x;
  int b = col >> 8, i = col & 255;
  const float* w = (b < 2) ? w3 : (b < 4) ? w4 : w5;
  const float* row = w + (size_t)i * 512 + (b & 1) * 256;
  float s = 0.f;
  for (int h = 0; h < HID; ++h) s += S[h] * row[h];
  SW[col] = s;
}

__global__ __launch_bounds__(256) void reduce_hs(
    const unsigned short* __restrict__ H1, float* __restrict__ hs)
{
  int bid = blockIdx.x;
  int c = bid >> 5, nch = bid & 31;
  int i = threadIdx.x;
  const unsigned short* p = H1 + (size_t)nch * 32 * NCLS * HID + (size_t)c * HID + i;
  float s = 0.f;
  for (int n = 0; n < 32; ++n) s += bf2f(p[(size_t)n * NCLS * HID]);
  atomicAdd(&hs[c * HID + i], s);
}

__global__ __launch_bounds__(256) void p2a(
    const float* __restrict__ hs, const float* __restrict__ w3,
    const float* __restrict__ w4, const float* __restrict__ w5, float* __restrict__ hsW)
{
  __shared__ float hrow[HID];
  int k = blockIdx.x & 127, b = blockIdx.x >> 7;
  int t = threadIdx.x;
  hrow[t] = hs[k * HID + t];
  __syncthreads();
  const float* w = (b < 2) ? w3 : (b < 4) ? w4 : w5;
  const float* row = w + (size_t)t * 512 + (b & 1) * 256;
  float s = 0.f;
  for (int h = 0; h < HID; ++h) s += hrow[h] * row[h];
  hsW[(size_t)k * 1536 + b * 256 + t] = s;
}

__global__ __launch_bounds__(256) void p2b(
    const float* __restrict__ hsW, const float* __restrict__ Kn,
    const float* __restrict__ b3, const float* __restrict__ b4, const float* __restrict__ b5,
    const float* __restrict__ bu3, const float* __restrict__ bu5, float* __restrict__ SG)
{
  __shared__ float kc[NCLS], kr[NCLS];
  int c = blockIdx.x, t = threadIdx.x;
  if (t < NCLS) { kc[t] = Kn[t * NCLS + c]; kr[t] = Kn[c * NCLS + t]; }
  __syncthreads();
  for (int g = 0; g < 3; ++g) {
    int i = t;
    const float* L = hsW + (size_t)(2 * g) * 256 + i;
    const float* R = hsW + (size_t)(2 * g + 1) * 256 + i;
    float s = 0.f;
    for (int k = 0; k < NCLS; ++k) s += kc[k] * L[(size_t)k * 1536] + kr[k] * R[(size_t)k * 1536];
    const float* bg = (g == 0) ? b3 : (g == 1) ? b4 : b5;
    s += bg[i] + ((g < 2) ? bu3[i] : bu5[i]);
    SG[(size_t)c * 768 + g * 256 + i] = s;
  }
}

// ---------------------------------------------------------------------------
extern "C" void kernel_launch(void* const* d_in, const int* in_sizes, int n_in,
                              void* d_out, int out_size, void* d_ws, size_t ws_size,
                              hipStream_t stream) {
  (void)in_sizes; (void)n_in; (void)out_size; (void)ws_size;
  const float* x   = (const float*)d_in[0];
  const float* Kn  = (const float*)d_in[1];
  const float* w3  = (const float*)d_in[2];
  const float* b3  = (const float*)d_in[3];
  const float* u3  = (const float*)d_in[4];
  const float* bu3 = (const float*)d_in[5];
  const float* w4  = (const float*)d_in[6];
  const float* b4  = (const float*)d_in[7];
  const float* w5  = (const float*)d_in[8];
  const float* b5  = (const float*)d_in[9];
  const float* u5  = (const float*)d_in[10];
  const float* bu5 = (const float*)d_in[11];
  float* out = (float*)d_out;

  char* w = (char*)d_ws;
  unsigned short* AVH = (unsigned short*)(w);                 // 131072x512 bf16 (128 MiB)
  unsigned short* PRE = (unsigned short*)(w + 134217728);     // 131072x768 bf16 (192 MiB)
  unsigned short* H1  = (unsigned short*)(w + 335544320);     // 64 MiB
  float*          XW  = (float*)(w + 402653184);              // 1024x1792 fp32
  char* misc = w + 409993216;
  float* S      = (float*)(misc);
  float* hs     = (float*)(misc + 1024);
  float* SW     = (float*)(misc + 132096);
  float* colsum = (float*)(misc + 138240);
  float* rowsum = (float*)(misc + 138752);
  float* hsW    = (float*)(misc + 139264);
  float* SG     = (float*)(misc + 925696);
  unsigned short* WB   = (unsigned short*)(misc + 1318912);
  unsigned short* WB2  = (unsigned short*)(misc + 2498560);
  unsigned short* u5b  = (unsigned short*)(misc + 3416064);
  unsigned short* KbN  = (unsigned short*)(misc + 3547136);
  unsigned short* KTbN = (unsigned short*)(misc + 3579904);
  unsigned short* xb   = (unsigned short*)(misc + 3612672);

  hipMemsetAsync(misc, 0, 132096, stream);  // S + hs

  prep_cast<<<5504, 256, 0, stream>>>(x, Kn, w3, u3, w4, w5, u5, xb, WB, WB2, u5b, KbN, KTbN);
  prep_reduce<<<10, 256, 0, stream>>>(x, Kn, S, colsum, rowsum);
  prep_sw<<<6, 256, 0, stream>>>(S, w3, w4, w5, SW);

  // XW = x @ Wcat^T  [1024,256]x[256,1792] -> fp32
  gemm_bf16<0><<<8 * 14, 256, 0, stream>>>(xb, 256, 256, xb, 256, WB2, 256, 0L,
                                           (void*)XW, 1792, 14, 256, 0xFFFFFFFFu, 8);
  // fused layer 1 -> H1 and AVH (mini-GEMMs in epilogue)
  gemm_l1<<<2048, 256, 0, stream>>>(XW, SW, x, b3, b4, b5, bu3, bu5,
                                    colsum, rowsum, u5b, KTbN, KbN, H1, AVH);

  reduce_hs<<<4096, 256, 0, stream>>>(H1, hs);
  p2a<<<768, 256, 0, stream>>>(hs, w3, w4, w5, hsW);
  p2b<<<128, 256, 0, stream>>>(hsW, Kn, b3, b4, b5, bu3, bu5, SG);

  // PRE (merged: 6 col-tiles, per-ct K)
  gemm_pre<<<6144, 256, 0, stream>>>(AVH, H1, WB, PRE);

  // fused layer 2 -> out
  gemm_l2<<<2048, 256, 0, stream>>>(PRE, SG, H1, u5b, out);
}